// Round 6
// baseline (389.747 us; speedup 1.0000x reference)
//
#include <hip/hip_runtime.h>

// CrossAttention: B=8, C=256, H=W=64, N=4096
// fp16 pipeline. attn v3: 4 waves x 32 queries/wave (each K/V LDS fragment
// feeds 2 MFMAs -> halves LDS-read bytes per FLOP; LDS port was the bound),
// KVBLK=64, dbuf 2x64KB LDS, 1 block/CU, 1 wave/SIMD (VGPR-heavy by design).
// Wq/bq pre-scaled by log2(e) -> exp2-based softmax.

#define C_DIM 256
#define N_DIM 4096

using f32x4 = __attribute__((ext_vector_type(4))) float;
using f16x8 = __attribute__((ext_vector_type(8))) _Float16;

__device__ __forceinline__ f32x4 mfmah(f16x8 a, f16x8 b, f32x4 c) {
  return __builtin_amdgcn_mfma_f32_16x16x32_f16(a, b, c, 0, 0, 0);
}
__device__ __forceinline__ unsigned int pk2(float a, float b) {
  return __builtin_bit_cast(unsigned int, __builtin_amdgcn_cvt_pkrtz(a, b));
}
__device__ __forceinline__ void gload_lds16(const void* g, void* l) {
  __builtin_amdgcn_global_load_lds(
      (const __attribute__((address_space(1))) unsigned int*)g,
      (__attribute__((address_space(3))) unsigned int*)l, 16, 0, 0);
}

// ---------------- kernel 1: convert W to fp16 (Wq scaled by log2e) --------
__global__ __launch_bounds__(256) void cvt_w3(const float* __restrict__ wq,
                                              const float* __restrict__ wk,
                                              const float* __restrict__ wv,
                                              _Float16* __restrict__ dst) {
  int i = blockIdx.x * 256 + threadIdx.x;  // 0..65535
  int m = blockIdx.y;                      // 0..2
  const float* w = (m == 0) ? wq : ((m == 1) ? wk : wv);
  float s = (m == 0) ? 1.4426950408889634f : 1.0f;  // fold log2e into Q path
  dst[m * 65536 + i] = (_Float16)(w[i] * s);
}

// ---------------- kernel 2: projections (fp16, single term) ----------------
// p=0: q=(Wq*log2e)*x1+bq*log2e -> qt [b][n][c];  p=1: k -> kt [b][n][c];
// p=2: v -> vv [b][c][n].
#define PROW 66
__global__ __launch_bounds__(256) void proj_kernel(
    const float* __restrict__ x1, const float* __restrict__ x2,
    const _Float16* __restrict__ wsp,
    const float* __restrict__ bq, const float* __restrict__ bk, const float* __restrict__ bv,
    _Float16* __restrict__ qt, _Float16* __restrict__ kt, _Float16* __restrict__ vv) {
  __shared__ __align__(16) _Float16 sx[256 * PROW];
  const int t = threadIdx.x;
  const int n0 = blockIdx.x * 64;
  const int b = blockIdx.y;
  const int p = blockIdx.z;
  const float* x = (p == 0) ? x1 : x2;
  const float* bias = (p == 0) ? bq : ((p == 1) ? bk : bv);
  const float bscale = (p == 0) ? 1.4426950408889634f : 1.0f;
  const _Float16* wp = wsp + p * 65536;

  for (int it = 0; it < 16; ++it) {
    int chunk = t + 256 * it;
    int row = chunk >> 4, n4 = chunk & 15;
    float4 v4 = *((const float4*)(x + ((size_t)b * 256 + row) * 4096 + n0) + n4);
    union { _Float16 h[4]; ushort4 u; } pk;
    pk.h[0] = (_Float16)v4.x; pk.h[1] = (_Float16)v4.y;
    pk.h[2] = (_Float16)v4.z; pk.h[3] = (_Float16)v4.w;
    *(ushort4*)(sx + row * PROW + n4 * 4) = pk.u;
  }
  __syncthreads();

  const int wv_ = t >> 6;
  const int lane = t & 63;
  const int li = lane & 15;
  const int lg = lane >> 4;
  const int nloc = wv_ * 16 + li;

  f16x8 xf[8];
  #pragma unroll
  for (int cs = 0; cs < 8; ++cs) {
    #pragma unroll
    for (int jj = 0; jj < 8; ++jj)
      xf[cs][jj] = sx[(cs * 32 + lg * 8 + jj) * PROW + nloc];
  }

  const int n = n0 + nloc;
  for (int ot = 0; ot < 16; ++ot) {
    f32x4 acc = 0.0f;
    const int ofr = ot * 16 + li;
    #pragma unroll
    for (int cs = 0; cs < 8; ++cs) {
      f16x8 wf = *(const f16x8*)(wp + ofr * 256 + cs * 32 + lg * 8);
      acc = mfmah(wf, xf[cs], acc);
    }
    if (p == 2) {
      #pragma unroll
      for (int r = 0; r < 4; ++r) {
        int o = ot * 16 + lg * 4 + r;
        vv[((size_t)b * 256 + o) * 4096 + n] = (_Float16)(acc[r] + bias[o]);
      }
    } else {
      _Float16* d = (p == 0) ? qt : kt;
      union { _Float16 h[4]; ushort4 u; } pk;
      #pragma unroll
      for (int r = 0; r < 4; ++r)
        pk.h[r] = (_Float16)(acc[r] + bias[ot * 16 + lg * 4 + r] * bscale);
      *(ushort4*)(d + ((size_t)b * 4096 + n) * 256 + ot * 16 + lg * 4) = pk.u;
    }
  }
}

// ---------------- kernel 3: flash attention (fp16, 32 q/wave) ----------------
// 256 threads (4 waves x 32 queries), grid (8 batches, 32 qblocks) = 1 blk/CU.
// KVBLK=64: K tile [64][256] (rows 512B, slot s16 = o16^(row&7));
//           V tile [256][64] (rows 128B, slot s8 = o8^(c&7)).
// Double buffer 2 x 64KB = 128KB LDS. Staged via global_load_lds with
// inverse-swizzled global source (linear LDS dst). exp2 softmax, defer-max.
#define NT 64
#define VOFF 32768
#define BUFSZ 65536

__global__ __launch_bounds__(256, 1) void attn_kernel(
    const _Float16* __restrict__ qtp, const _Float16* __restrict__ ktp,
    const _Float16* __restrict__ vvp, float* __restrict__ out) {
  __shared__ __align__(16) char lds[2 * BUFSZ];

  const int tid = threadIdx.x;
  const int b = blockIdx.x;
  const int w = tid >> 6;
  const int lane = tid & 63;
  const int li = lane & 15;
  const int lg = lane >> 4;
  const int q0 = blockIdx.y * 128 + w * 32;   // wave covers queries q0..q0+31

  // Q fragments: 2 q-tiles x 256 ch fp16 (64 VGPRs)
  f16x8 qf[2][8];
  #pragma unroll
  for (int qi = 0; qi < 2; ++qi) {
    const size_t qrow = ((size_t)b * N_DIM + q0 + qi * 16 + li) * C_DIM;
    #pragma unroll
    for (int cs = 0; cs < 8; ++cs)
      qf[qi][cs] = *(const f16x8*)(qtp + qrow + cs * 32 + lg * 8);
  }

  f32x4 acc[2][16];
  #pragma unroll
  for (int qi = 0; qi < 2; ++qi)
    #pragma unroll
    for (int ct = 0; ct < 16; ++ct) acc[qi][ct] = 0.0f;
  float m_run[2] = {-1e30f, -1e30f};
  float l_run[2] = {0.f, 0.f};

  // stage one 64-key tile (K 32KB + V 32KB); 16 gload_lds per thread
#define STAGE(BUF, KT)                                                        \
  {                                                                           \
    int k0_ = (KT) * 64;                                                      \
    char* bb = lds + (BUF) * BUFSZ;                                           \
    _Pragma("unroll")                                                         \
    for (int j = 0; j < 8; ++j) {                                             \
      int l = j * 256 + tid;              /* K chunk 0..2047 */               \
      int row = l >> 5, s16 = l & 31;                                         \
      int o16 = s16 ^ (row & 7);                                              \
      size_t gk = ((size_t)b * N_DIM + k0_ + row) * C_DIM + o16 * 8;          \
      gload_lds16(ktp + gk, bb + l * 16);                                     \
      int c = l >> 3, s8 = l & 7;         /* V chunk */                       \
      int o8 = s8 ^ (c & 7);                                                  \
      size_t gv = ((size_t)b * C_DIM + c) * N_DIM + k0_ + o8 * 8;             \
      gload_lds16(vvp + gv, bb + VOFF + l * 16);                              \
    }                                                                         \
  }

  STAGE(0, 0)
  int cur = 0;

  for (int kt = 0; kt < NT; ++kt) {
    __syncthreads();                 // buf[cur] DMA drained; prev compute done
    if (kt + 1 < NT) STAGE(cur ^ 1, kt + 1)
    const char* bb = lds + cur * BUFSZ;

    #pragma unroll
    for (int sub = 0; sub < 2; ++sub) {
      // QK^T (swapped): each K fragment feeds both q-tiles
      f32x4 st[2][2];
      st[0][0] = 0.0f; st[0][1] = 0.0f; st[1][0] = 0.0f; st[1][1] = 0.0f;
      #pragma unroll
      for (int cs = 0; cs < 8; ++cs) {
        int r0 = sub * 32 + li;
        int r1 = r0 + 16;
        f16x8 k0f = *(const f16x8*)(bb + r0 * 512 + (((cs * 4 + lg) ^ (r0 & 7)) * 16));
        f16x8 k1f = *(const f16x8*)(bb + r1 * 512 + (((cs * 4 + lg) ^ (r1 & 7)) * 16));
        st[0][0] = mfmah(k0f, qf[0][cs], st[0][0]);
        st[1][0] = mfmah(k0f, qf[1][cs], st[1][0]);
        st[0][1] = mfmah(k1f, qf[0][cs], st[0][1]);
        st[1][1] = mfmah(k1f, qf[1][cs], st[1][1]);
      }

      // softmax (exp2 units; defer-max THR = 8*log2e) + P pack/permute
      f16x8 puv[2];
      #pragma unroll
      for (int qi = 0; qi < 2; ++qi) {
        float s0 = st[qi][0][0], s1 = st[qi][0][1], s2 = st[qi][0][2], s3 = st[qi][0][3];
        float s4 = st[qi][1][0], s5 = st[qi][1][1], s6 = st[qi][1][2], s7 = st[qi][1][3];
        float tmax = fmaxf(fmaxf(fmaxf(s0, s1), fmaxf(s2, s3)),
                           fmaxf(fmaxf(s4, s5), fmaxf(s6, s7)));
        tmax = fmaxf(tmax, __shfl_xor(tmax, 16));
        tmax = fmaxf(tmax, __shfl_xor(tmax, 32));
        if (tmax > m_run[qi] + 11.541560f) {
          float sc = exp2f(m_run[qi] - tmax);
          m_run[qi] = tmax;
          l_run[qi] *= sc;
          #pragma unroll
          for (int ct = 0; ct < 16; ++ct) {
            acc[qi][ct][0] *= sc; acc[qi][ct][1] *= sc;
            acc[qi][ct][2] *= sc; acc[qi][ct][3] *= sc;
          }
        }
        float e0 = exp2f(s0 - m_run[qi]), e1 = exp2f(s1 - m_run[qi]);
        float e2 = exp2f(s2 - m_run[qi]), e3 = exp2f(s3 - m_run[qi]);
        float e4 = exp2f(s4 - m_run[qi]), e5 = exp2f(s5 - m_run[qi]);
        float e6 = exp2f(s6 - m_run[qi]), e7 = exp2f(s7 - m_run[qi]);
        float ts = ((e0 + e1) + (e2 + e3)) + ((e4 + e5) + (e6 + e7));
        ts += __shfl_xor(ts, 16);
        ts += __shfl_xor(ts, 32);
        l_run[qi] += ts;

        unsigned int W00 = pk2(e0, e1), W01 = pk2(e2, e3);
        unsigned int W10 = pk2(e4, e5), W11 = pk2(e6, e7);
        int srcA = li + 32 * (lg & 1);
        int srcB = srcA + 16;
        unsigned int a00 = __shfl(W00, srcA), a01 = __shfl(W01, srcA);
        unsigned int a10 = __shfl(W10, srcA), a11 = __shfl(W11, srcA);
        unsigned int b00 = __shfl(W00, srcB), b01 = __shfl(W01, srcB);
        unsigned int b10 = __shfl(W10, srcB), b11 = __shfl(W11, srcB);
        bool h2 = (lg >> 1) != 0;
        union { unsigned int u[4]; f16x8 v; } pu;
        pu.u[0] = h2 ? a10 : a00;
        pu.u[1] = h2 ? a11 : a01;
        pu.u[2] = h2 ? b10 : b00;
        pu.u[3] = h2 ? b11 : b01;
        puv[qi] = pu.v;
      }

      // PV: each V fragment feeds both q-tiles
      #pragma unroll
      for (int ct = 0; ct < 16; ++ct) {
        int c = ct * 16 + li;
        int s = (sub * 4 + lg) ^ (c & 7);
        f16x8 vf = *(const f16x8*)(bb + VOFF + c * 128 + s * 16);
        acc[0][ct] = mfmah(vf, puv[0], acc[0][ct]);
        acc[1][ct] = mfmah(vf, puv[1], acc[1][ct]);
      }
    }

    cur ^= 1;
  }

  // epilogue: normalize and store out[b][c][n] fp32
  #pragma unroll
  for (int qi = 0; qi < 2; ++qi) {
    float inv = 1.0f / l_run[qi];
    #pragma unroll
    for (int ct = 0; ct < 16; ++ct) {
      #pragma unroll
      for (int r = 0; r < 4; ++r) {
        int c = ct * 16 + lg * 4 + r;
        out[((size_t)b * C_DIM + c) * N_DIM + q0 + qi * 16 + li] = acc[qi][ct][r] * inv;
      }
    }
  }
#undef STAGE
}

extern "C" void kernel_launch(void* const* d_in, const int* in_sizes, int n_in,
                              void* d_out, int out_size, void* d_ws, size_t ws_size,
                              hipStream_t stream) {
  const float* x1 = (const float*)d_in[0];
  const float* x2 = (const float*)d_in[1];
  const float* Wq = (const float*)d_in[2];
  const float* bq = (const float*)d_in[3];
  const float* Wk = (const float*)d_in[4];
  const float* bk = (const float*)d_in[5];
  const float* Wv = (const float*)d_in[6];
  const float* bv = (const float*)d_in[7];
  float* out = (float*)d_out;

  char* ws = (char*)d_ws;
  const size_t SZ = (size_t)8 * 4096 * 256 * 2;  // 16.78 MB per fp16 plane
  _Float16* qt  = (_Float16*)(ws + 0 * SZ);
  _Float16* kt  = (_Float16*)(ws + 1 * SZ);
  _Float16* vv  = (_Float16*)(ws + 2 * SZ);
  _Float16* wsp = (_Float16*)(ws + 3 * SZ);  // 3*65536 fp16 = 384KB
  // requires ws_size >= 3*SZ + 393216 = 50,724,864 bytes

  cvt_w3<<<dim3(256, 3), 256, 0, stream>>>(Wq, Wk, Wv, wsp);
  proj_kernel<<<dim3(64, 8, 3), 256, 0, stream>>>(x1, x2, wsp, bq, bk, bv,
                                                  qt, kt, vv);
  attn_kernel<<<dim3(8, 32), 256, 0, stream>>>(qt, kt, vv, out);
}

// Round 7
// 328.730 us; speedup vs baseline: 1.1856x; 1.1856x over previous
//
#include <hip/hip_runtime.h>

// CrossAttention: B=8, C=256, H=W=64, N=4096
// fp16 pipeline, round 7:
//   cvt_w3 -> proj3_kernel (all 3 projections per block; x2 staged once for
//   K and V) -> attn_kernel (2q/wave, KVBLK=32, KEY-SPLIT x2 so 2048 waves
//   = 8 waves/CU; partial per-half outputs) -> merge_kernel.

#define C_DIM 256
#define N_DIM 4096
#define LOG2E 1.4426950408889634f

using f32x4 = __attribute__((ext_vector_type(4))) float;
using f16x8 = __attribute__((ext_vector_type(8))) _Float16;

__device__ __forceinline__ f32x4 mfmah(f16x8 a, f16x8 b, f32x4 c) {
  return __builtin_amdgcn_mfma_f32_16x16x32_f16(a, b, c, 0, 0, 0);
}
__device__ __forceinline__ unsigned int pk2(float a, float b) {
  return __builtin_bit_cast(unsigned int, __builtin_amdgcn_cvt_pkrtz(a, b));
}
__device__ __forceinline__ void gload_lds16(const void* g, void* l) {
  __builtin_amdgcn_global_load_lds(
      (const __attribute__((address_space(1))) unsigned int*)g,
      (__attribute__((address_space(3))) unsigned int*)l, 16, 0, 0);
}

// ---------------- kernel 1: convert W to fp16 (Wq scaled by log2e) --------
__global__ __launch_bounds__(256) void cvt_w3(const float* __restrict__ wq,
                                              const float* __restrict__ wk,
                                              const float* __restrict__ wv,
                                              _Float16* __restrict__ dst) {
  int i = blockIdx.x * 256 + threadIdx.x;  // 0..65535
  int m = blockIdx.y;                      // 0..2
  const float* w = (m == 0) ? wq : ((m == 1) ? wk : wv);
  float s = (m == 0) ? LOG2E : 1.0f;
  dst[m * 65536 + i] = (_Float16)(w[i] * s);
}

// ---------------- kernel 2: all 3 projections ----------------
// grid (32 n-tiles, 8 batches), 512 thr (8 waves x 16 cols = 128 cols).
// Stage x1 -> Q; stage x2 once -> K and V (shared gathered fragments).
#define PROW2 130
__global__ __launch_bounds__(512) void proj3_kernel(
    const float* __restrict__ x1, const float* __restrict__ x2,
    const _Float16* __restrict__ wsp,
    const float* __restrict__ bq, const float* __restrict__ bk, const float* __restrict__ bv,
    _Float16* __restrict__ qt, _Float16* __restrict__ kt, _Float16* __restrict__ vv) {
  __shared__ __align__(16) _Float16 sx[256 * PROW2];
  const int t = threadIdx.x;
  const int n0 = blockIdx.x * 128;
  const int b = blockIdx.y;

  const int w = t >> 6;
  const int lane = t & 63;
  const int li = lane & 15;
  const int lg = lane >> 4;
  const int nloc = w * 16 + li;
  const int n = n0 + nloc;

#define STAGEX(XP)                                                          \
  for (int it = 0; it < 16; ++it) {                                        \
    int chunk = t + 512 * it;                                              \
    int row = chunk >> 5, n4 = chunk & 31;                                 \
    float4 v4 = *((const float4*)((XP) + ((size_t)b * 256 + row) * 4096 + n0) + n4); \
    union { _Float16 h[4]; ushort4 u; } pk;                                \
    pk.h[0] = (_Float16)v4.x; pk.h[1] = (_Float16)v4.y;                    \
    pk.h[2] = (_Float16)v4.z; pk.h[3] = (_Float16)v4.w;                    \
    *(ushort4*)(sx + row * PROW2 + n4 * 4) = pk.u;                         \
  }

#define GATHER(XF)                                                          \
  _Pragma("unroll")                                                         \
  for (int cs = 0; cs < 8; ++cs) {                                         \
    _Pragma("unroll")                                                       \
    for (int jj = 0; jj < 8; ++jj)                                         \
      XF[cs][jj] = sx[(cs * 32 + lg * 8 + jj) * PROW2 + nloc];             \
  }

  // ---- x1 -> Q ----
  STAGEX(x1)
  __syncthreads();
  f16x8 xf[8];
  GATHER(xf)
  {
    const _Float16* wp = wsp;  // Wq (pre-scaled by log2e)
    for (int ot = 0; ot < 16; ++ot) {
      f32x4 acc = 0.0f;
      const int ofr = ot * 16 + li;
      #pragma unroll
      for (int cs = 0; cs < 8; ++cs) {
        f16x8 wf = *(const f16x8*)(wp + ofr * 256 + cs * 32 + lg * 8);
        acc = mfmah(wf, xf[cs], acc);
      }
      union { _Float16 h[4]; ushort4 u; } pk;
      #pragma unroll
      for (int r = 0; r < 4; ++r)
        pk.h[r] = (_Float16)(acc[r] + bq[ot * 16 + lg * 4 + r] * LOG2E);
      *(ushort4*)(qt + ((size_t)b * 4096 + n) * 256 + ot * 16 + lg * 4) = pk.u;
    }
  }
  __syncthreads();

  // ---- x2 -> K and V (one stage+gather, two GEMMs) ----
  STAGEX(x2)
  __syncthreads();
  GATHER(xf)
  {
    const _Float16* wp = wsp + 65536;  // Wk
    for (int ot = 0; ot < 16; ++ot) {
      f32x4 acc = 0.0f;
      const int ofr = ot * 16 + li;
      #pragma unroll
      for (int cs = 0; cs < 8; ++cs) {
        f16x8 wf = *(const f16x8*)(wp + ofr * 256 + cs * 32 + lg * 8);
        acc = mfmah(wf, xf[cs], acc);
      }
      union { _Float16 h[4]; ushort4 u; } pk;
      #pragma unroll
      for (int r = 0; r < 4; ++r)
        pk.h[r] = (_Float16)(acc[r] + bk[ot * 16 + lg * 4 + r]);
      *(ushort4*)(kt + ((size_t)b * 4096 + n) * 256 + ot * 16 + lg * 4) = pk.u;
    }
    wp = wsp + 131072;  // Wv
    for (int ot = 0; ot < 16; ++ot) {
      f32x4 acc = 0.0f;
      const int ofr = ot * 16 + li;
      #pragma unroll
      for (int cs = 0; cs < 8; ++cs) {
        f16x8 wf = *(const f16x8*)(wp + ofr * 256 + cs * 32 + lg * 8);
        acc = mfmah(wf, xf[cs], acc);
      }
      #pragma unroll
      for (int r = 0; r < 4; ++r) {
        int o = ot * 16 + lg * 4 + r;
        vv[((size_t)b * 256 + o) * 4096 + n] = (_Float16)(acc[r] + bv[o]);
      }
    }
  }
#undef STAGEX
#undef GATHER
}

// ---------------- kernel 3: flash attention (2q/wave, key-split x2) -------
// grid (16 = b*2+half, 32 qblocks), 256 thr (4 waves x 32 q = 128 q).
// Each block: 2048 keys, KVBLK=32, dbuf 2x32KB LDS -> 2 blocks/CU, 8 w/CU.
// Outputs NORMALIZED o (fp16) + (m, l) per q for the merge pass.
#define NT 64
#define VOFF 16384
#define BUFSZ 32768

__global__ __launch_bounds__(256, 2) void attn_kernel(
    const _Float16* __restrict__ qtp, const _Float16* __restrict__ ktp,
    const _Float16* __restrict__ vvp, _Float16* __restrict__ op,
    float2* __restrict__ ml) {
  __shared__ __align__(16) char lds[2 * BUFSZ];

  const int tid = threadIdx.x;
  const int half = blockIdx.x & 1;
  const int b = blockIdx.x >> 1;
  const int koff = half * 2048;
  const int w = tid >> 6;
  const int lane = tid & 63;
  const int li = lane & 15;
  const int lg = lane >> 4;
  const int q0 = blockIdx.y * 128 + w * 32;

  // Q fragments: 2 q-tiles x 256 ch fp16 (64 VGPRs)
  f16x8 qf[2][8];
  #pragma unroll
  for (int qi = 0; qi < 2; ++qi) {
    const size_t qrow = ((size_t)b * N_DIM + q0 + qi * 16 + li) * C_DIM;
    #pragma unroll
    for (int cs = 0; cs < 8; ++cs)
      qf[qi][cs] = *(const f16x8*)(qtp + qrow + cs * 32 + lg * 8);
  }

  f32x4 acc[2][16];
  #pragma unroll
  for (int qi = 0; qi < 2; ++qi)
    #pragma unroll
    for (int ct = 0; ct < 16; ++ct) acc[qi][ct] = 0.0f;
  float m_run[2] = {-1e30f, -1e30f};
  float l_run[2] = {0.f, 0.f};

  // stage one 32-key tile (K 16KB + V 16KB); 8 gloads per thread
#define STAGE(BUF, KT)                                                        \
  {                                                                           \
    int k0_ = koff + (KT) * 32;                                               \
    char* bb = lds + (BUF) * BUFSZ;                                           \
    _Pragma("unroll")                                                         \
    for (int j = 0; j < 4; ++j) {                                             \
      int l = j * 256 + tid;              /* 0..1023 */                       \
      int row = l >> 5, s16 = l & 31;                                         \
      int o16 = s16 ^ (row & 7);                                              \
      size_t gk = ((size_t)b * N_DIM + k0_ + row) * C_DIM + o16 * 8;          \
      gload_lds16(ktp + gk, bb + l * 16);                                     \
      int c = l >> 2, s4 = l & 3;                                             \
      int o4 = s4 ^ ((c >> 1) & 3);                                           \
      size_t gv = ((size_t)b * C_DIM + c) * N_DIM + k0_ + o4 * 8;             \
      gload_lds16(vvp + gv, bb + VOFF + l * 16);                              \
    }                                                                         \
  }

  STAGE(0, 0)
  int cur = 0;

  for (int kt = 0; kt < NT; ++kt) {
    __syncthreads();                 // buf[cur] DMA drained; prev compute done
    if (kt + 1 < NT) STAGE(cur ^ 1, kt + 1)
    const char* bb = lds + cur * BUFSZ;

    // QK^T (swapped): each K fragment feeds both q-tiles
    f32x4 st[2][2];
    st[0][0] = 0.0f; st[0][1] = 0.0f; st[1][0] = 0.0f; st[1][1] = 0.0f;
    #pragma unroll
    for (int cs = 0; cs < 8; ++cs) {
      int r0 = li, r1 = li + 16;
      f16x8 k0f = *(const f16x8*)(bb + r0 * 512 + (((cs * 4 + lg) ^ (r0 & 7)) * 16));
      f16x8 k1f = *(const f16x8*)(bb + r1 * 512 + (((cs * 4 + lg) ^ (r1 & 7)) * 16));
      st[0][0] = mfmah(k0f, qf[0][cs], st[0][0]);
      st[1][0] = mfmah(k0f, qf[1][cs], st[1][0]);
      st[0][1] = mfmah(k1f, qf[0][cs], st[0][1]);
      st[1][1] = mfmah(k1f, qf[1][cs], st[1][1]);
    }

    // softmax (exp2 units; defer-max THR = 8*log2e) + P pack/permute
    f16x8 puv[2];
    #pragma unroll
    for (int qi = 0; qi < 2; ++qi) {
      float s0 = st[qi][0][0], s1 = st[qi][0][1], s2 = st[qi][0][2], s3 = st[qi][0][3];
      float s4 = st[qi][1][0], s5 = st[qi][1][1], s6 = st[qi][1][2], s7 = st[qi][1][3];
      float tmax = fmaxf(fmaxf(fmaxf(s0, s1), fmaxf(s2, s3)),
                         fmaxf(fmaxf(s4, s5), fmaxf(s6, s7)));
      tmax = fmaxf(tmax, __shfl_xor(tmax, 16));
      tmax = fmaxf(tmax, __shfl_xor(tmax, 32));
      if (tmax > m_run[qi] + 11.541560f) {
        float sc = exp2f(m_run[qi] - tmax);
        m_run[qi] = tmax;
        l_run[qi] *= sc;
        #pragma unroll
        for (int ct = 0; ct < 16; ++ct) {
          acc[qi][ct][0] *= sc; acc[qi][ct][1] *= sc;
          acc[qi][ct][2] *= sc; acc[qi][ct][3] *= sc;
        }
      }
      float e0 = exp2f(s0 - m_run[qi]), e1 = exp2f(s1 - m_run[qi]);
      float e2 = exp2f(s2 - m_run[qi]), e3 = exp2f(s3 - m_run[qi]);
      float e4 = exp2f(s4 - m_run[qi]), e5 = exp2f(s5 - m_run[qi]);
      float e6 = exp2f(s6 - m_run[qi]), e7 = exp2f(s7 - m_run[qi]);
      float ts = ((e0 + e1) + (e2 + e3)) + ((e4 + e5) + (e6 + e7));
      ts += __shfl_xor(ts, 16);
      ts += __shfl_xor(ts, 32);
      l_run[qi] += ts;

      unsigned int W00 = pk2(e0, e1), W01 = pk2(e2, e3);
      unsigned int W10 = pk2(e4, e5), W11 = pk2(e6, e7);
      int srcA = li + 32 * (lg & 1);
      int srcB = srcA + 16;
      unsigned int a00 = __shfl(W00, srcA), a01 = __shfl(W01, srcA);
      unsigned int a10 = __shfl(W10, srcA), a11 = __shfl(W11, srcA);
      unsigned int b00 = __shfl(W00, srcB), b01 = __shfl(W01, srcB);
      unsigned int b10 = __shfl(W10, srcB), b11 = __shfl(W11, srcB);
      bool h2 = (lg >> 1) != 0;
      union { unsigned int u[4]; f16x8 v; } pu;
      pu.u[0] = h2 ? a10 : a00;
      pu.u[1] = h2 ? a11 : a01;
      pu.u[2] = h2 ? b10 : b00;
      pu.u[3] = h2 ? b11 : b01;
      puv[qi] = pu.v;
    }

    // PV: each V fragment feeds both q-tiles
    #pragma unroll
    for (int ct = 0; ct < 16; ++ct) {
      int c = ct * 16 + li;
      int off = c * 64 + ((lg ^ ((c >> 1) & 3)) * 16);
      f16x8 vf = *(const f16x8*)(bb + VOFF + off);
      acc[0][ct] = mfmah(vf, puv[0], acc[0][ct]);
      acc[1][ct] = mfmah(vf, puv[1], acc[1][ct]);
    }

    cur ^= 1;
  }

  // epilogue: normalized partial o (fp16) + (m,l) per q
  _Float16* opb = op + (size_t)(half * 8 + b) * C_DIM * N_DIM;
  #pragma unroll
  for (int qi = 0; qi < 2; ++qi) {
    float inv = 1.0f / l_run[qi];
    int n = q0 + qi * 16 + li;
    #pragma unroll
    for (int ct = 0; ct < 16; ++ct) {
      #pragma unroll
      for (int r = 0; r < 4; ++r) {
        int c = ct * 16 + lg * 4 + r;
        opb[(size_t)c * N_DIM + n] = (_Float16)(acc[qi][ct][r] * inv);
      }
    }
  }
  if (lg == 0) {
    #pragma unroll
    for (int qi = 0; qi < 2; ++qi) {
      int q = q0 + qi * 16 + li;
      ml[(size_t)(half * 8 + b) * N_DIM + q] = make_float2(m_run[qi], l_run[qi]);
    }
  }
#undef STAGE
}

// ---------------- kernel 4: merge the two key-halves ----------------
// grid (8, 32), 256 thr. out = a0*o0 + a1*o1, a_h = l_h*2^(m_h-M)/L.
__global__ __launch_bounds__(256) void merge_kernel(
    const _Float16* __restrict__ op, const float2* __restrict__ ml,
    float* __restrict__ out) {
  const int b = blockIdx.x;
  const int n0 = blockIdx.y * 128;
  const int tid = threadIdx.x;
  const int nc = tid & 15;        // n-chunk of 8
  const int cl = tid >> 4;        // c lane
  const int nb = n0 + nc * 8;

  float a0[8], a1[8];
  #pragma unroll
  for (int jj = 0; jj < 8; ++jj) {
    int q = nb + jj;
    float2 h0 = ml[(size_t)b * N_DIM + q];
    float2 h1 = ml[(size_t)(8 + b) * N_DIM + q];
    float M = fmaxf(h0.x, h1.x);
    float e0 = exp2f(h0.x - M) * h0.y;
    float e1 = exp2f(h1.x - M) * h1.y;
    float inv = 1.0f / (e0 + e1);
    a0[jj] = e0 * inv;
    a1[jj] = e1 * inv;
  }
  const _Float16* op0 = op + (size_t)b * C_DIM * N_DIM;
  const _Float16* op1 = op + (size_t)(8 + b) * C_DIM * N_DIM;
  for (int it = 0; it < 16; ++it) {
    int c = cl + it * 16;
    size_t base = (size_t)c * N_DIM + nb;
    f16x8 p0 = *(const f16x8*)(op0 + base);
    f16x8 p1 = *(const f16x8*)(op1 + base);
    float o[8];
    #pragma unroll
    for (int jj = 0; jj < 8; ++jj)
      o[jj] = (float)p0[jj] * a0[jj] + (float)p1[jj] * a1[jj];
    size_t ob = ((size_t)b * C_DIM + c) * N_DIM + nb;
    *(float4*)(out + ob) = make_float4(o[0], o[1], o[2], o[3]);
    *(float4*)(out + ob + 4) = make_float4(o[4], o[5], o[6], o[7]);
  }
}

extern "C" void kernel_launch(void* const* d_in, const int* in_sizes, int n_in,
                              void* d_out, int out_size, void* d_ws, size_t ws_size,
                              hipStream_t stream) {
  const float* x1 = (const float*)d_in[0];
  const float* x2 = (const float*)d_in[1];
  const float* Wq = (const float*)d_in[2];
  const float* bq = (const float*)d_in[3];
  const float* Wk = (const float*)d_in[4];
  const float* bk = (const float*)d_in[5];
  const float* Wv = (const float*)d_in[6];
  const float* bv = (const float*)d_in[7];
  float* out = (float*)d_out;

  char* ws = (char*)d_ws;
  const size_t SZ = (size_t)8 * 4096 * 256 * 2;  // 16.78 MB per fp16 plane
  _Float16* qt  = (_Float16*)(ws + 0 * SZ);
  _Float16* kt  = (_Float16*)(ws + 1 * SZ);
  _Float16* vv  = (_Float16*)(ws + 2 * SZ);
  _Float16* op  = (_Float16*)(ws + 3 * SZ);     // 2 x SZ partial outputs
  float2*   ml  = (float2*)(ws + 5 * SZ);       // 2*8*4096*8B = 512KB
  _Float16* wsp = (_Float16*)(ws + 3 * SZ);     // overlaps op: proj before attn
  // requires ws_size >= 5*SZ + 524288 = 84,410,368 bytes

  cvt_w3<<<dim3(256, 3), 256, 0, stream>>>(Wq, Wk, Wv, wsp);
  proj3_kernel<<<dim3(32, 8), 512, 0, stream>>>(x1, x2, wsp, bq, bk, bv,
                                                qt, kt, vv);
  attn_kernel<<<dim3(16, 32), 256, 0, stream>>>(qt, kt, vv, op, ml);
  merge_kernel<<<dim3(8, 32), 256, 0, stream>>>(op, ml, out);
}

// Round 8
// 287.438 us; speedup vs baseline: 1.3559x; 1.1437x over previous
//
#include <hip/hip_runtime.h>

// CrossAttention: B=8, C=256, H=W=64, N=4096
// fp16 pipeline, round 8:
//   cvt_w3 -> proj3_kernel -> attn_kernel (32x32x16 MFMA, 32q/wave,
//   key-split x2, strength-reduced addressing) -> merge_kernel.

#define C_DIM 256
#define N_DIM 4096
#define LOG2E 1.4426950408889634f

using f32x4 = __attribute__((ext_vector_type(4))) float;
using f32x16 = __attribute__((ext_vector_type(16))) float;
using f16x8 = __attribute__((ext_vector_type(8))) _Float16;

__device__ __forceinline__ f32x4 mfmah(f16x8 a, f16x8 b, f32x4 c) {
  return __builtin_amdgcn_mfma_f32_16x16x32_f16(a, b, c, 0, 0, 0);
}
__device__ __forceinline__ f32x16 mfma32(f16x8 a, f16x8 b, f32x16 c) {
  return __builtin_amdgcn_mfma_f32_32x32x16_f16(a, b, c, 0, 0, 0);
}
__device__ __forceinline__ unsigned int pk2(float a, float b) {
  return __builtin_bit_cast(unsigned int, __builtin_amdgcn_cvt_pkrtz(a, b));
}
__device__ __forceinline__ void gload_lds16(const void* g, void* l) {
  __builtin_amdgcn_global_load_lds(
      (const __attribute__((address_space(1))) unsigned int*)g,
      (__attribute__((address_space(3))) unsigned int*)l, 16, 0, 0);
}

// ---------------- kernel 1: convert W to fp16 (Wq scaled by log2e) --------
__global__ __launch_bounds__(256) void cvt_w3(const float* __restrict__ wq,
                                              const float* __restrict__ wk,
                                              const float* __restrict__ wv,
                                              _Float16* __restrict__ dst) {
  int i = blockIdx.x * 256 + threadIdx.x;
  int m = blockIdx.y;
  const float* w = (m == 0) ? wq : ((m == 1) ? wk : wv);
  float s = (m == 0) ? LOG2E : 1.0f;
  dst[m * 65536 + i] = (_Float16)(w[i] * s);
}

// ---------------- kernel 2: all 3 projections ----------------
#define PROW2 130
__global__ __launch_bounds__(512) void proj3_kernel(
    const float* __restrict__ x1, const float* __restrict__ x2,
    const _Float16* __restrict__ wsp,
    const float* __restrict__ bq, const float* __restrict__ bk, const float* __restrict__ bv,
    _Float16* __restrict__ qt, _Float16* __restrict__ kt, _Float16* __restrict__ vv) {
  __shared__ __align__(16) _Float16 sx[256 * PROW2];
  const int t = threadIdx.x;
  const int n0 = blockIdx.x * 128;
  const int b = blockIdx.y;

  const int w = t >> 6;
  const int lane = t & 63;
  const int li = lane & 15;
  const int lg = lane >> 4;
  const int nloc = w * 16 + li;
  const int n = n0 + nloc;

#define STAGEX(XP)                                                          \
  for (int it = 0; it < 16; ++it) {                                        \
    int chunk = t + 512 * it;                                              \
    int row = chunk >> 5, n4 = chunk & 31;                                 \
    float4 v4 = *((const float4*)((XP) + ((size_t)b * 256 + row) * 4096 + n0) + n4); \
    uint2 pv = make_uint2(pk2(v4.x, v4.y), pk2(v4.z, v4.w));               \
    *(uint2*)(sx + row * PROW2 + n4 * 4) = pv;                             \
  }

#define GATHER(XF)                                                          \
  _Pragma("unroll")                                                         \
  for (int cs = 0; cs < 8; ++cs) {                                         \
    _Pragma("unroll")                                                       \
    for (int jj = 0; jj < 8; ++jj)                                         \
      XF[cs][jj] = sx[(cs * 32 + lg * 8 + jj) * PROW2 + nloc];             \
  }

  // ---- x1 -> Q ----
  STAGEX(x1)
  __syncthreads();
  f16x8 xf[8];
  GATHER(xf)
  {
    const _Float16* wp = wsp;  // Wq (pre-scaled by log2e)
    for (int ot = 0; ot < 16; ++ot) {
      f32x4 acc = 0.0f;
      const int ofr = ot * 16 + li;
      #pragma unroll
      for (int cs = 0; cs < 8; ++cs) {
        f16x8 wf = *(const f16x8*)(wp + ofr * 256 + cs * 32 + lg * 8);
        acc = mfmah(wf, xf[cs], acc);
      }
      union { _Float16 h[4]; ushort4 u; } pk;
      #pragma unroll
      for (int r = 0; r < 4; ++r)
        pk.h[r] = (_Float16)(acc[r] + bq[ot * 16 + lg * 4 + r] * LOG2E);
      *(ushort4*)(qt + ((size_t)b * 4096 + n) * 256 + ot * 16 + lg * 4) = pk.u;
    }
  }
  __syncthreads();

  // ---- x2 -> K and V ----
  STAGEX(x2)
  __syncthreads();
  GATHER(xf)
  {
    const _Float16* wp = wsp + 65536;  // Wk
    for (int ot = 0; ot < 16; ++ot) {
      f32x4 acc = 0.0f;
      const int ofr = ot * 16 + li;
      #pragma unroll
      for (int cs = 0; cs < 8; ++cs) {
        f16x8 wf = *(const f16x8*)(wp + ofr * 256 + cs * 32 + lg * 8);
        acc = mfmah(wf, xf[cs], acc);
      }
      union { _Float16 h[4]; ushort4 u; } pk;
      #pragma unroll
      for (int r = 0; r < 4; ++r)
        pk.h[r] = (_Float16)(acc[r] + bk[ot * 16 + lg * 4 + r]);
      *(ushort4*)(kt + ((size_t)b * 4096 + n) * 256 + ot * 16 + lg * 4) = pk.u;
    }
    wp = wsp + 131072;  // Wv
    for (int ot = 0; ot < 16; ++ot) {
      f32x4 acc = 0.0f;
      const int ofr = ot * 16 + li;
      #pragma unroll
      for (int cs = 0; cs < 8; ++cs) {
        f16x8 wf = *(const f16x8*)(wp + ofr * 256 + cs * 32 + lg * 8);
        acc = mfmah(wf, xf[cs], acc);
      }
      #pragma unroll
      for (int r = 0; r < 4; ++r) {
        int o = ot * 16 + lg * 4 + r;
        vv[((size_t)b * 256 + o) * 4096 + n] = (_Float16)(acc[r] + bv[o]);
      }
    }
  }
#undef STAGEX
#undef GATHER
}

// ---------------- kernel 3: flash attention (32x32x16, key-split x2) -------
// grid (16 = b*2+half, 32 qblocks), 256 thr (4 waves x 32 q).
// K tile [32][256] rows 512B, slot s16 = o16^(row&7).
// V tile [256][32] rows 64B, slot s4 = o4^((c>>1)&3).
// All LDS read addresses = 6 per-lane bases + compile-time immediates.
#define NT 64
#define VOFF 16384
#define BUFSZ 32768

__global__ __launch_bounds__(256, 2) void attn_kernel(
    const _Float16* __restrict__ qtp, const _Float16* __restrict__ ktp,
    const _Float16* __restrict__ vvp, _Float16* __restrict__ op,
    float2* __restrict__ ml) {
  __shared__ __align__(16) char lds[2 * BUFSZ];

  const int tid = threadIdx.x;
  const int half = blockIdx.x & 1;
  const int b = blockIdx.x >> 1;
  const int w = tid >> 6;
  const int lane = tid & 63;
  const int qv = lane & 31;          // this lane's q column
  const int hi = lane >> 5;
  const int xx = (lane >> 1) & 3;    // lane-invariant swizzle bits
  const int q0 = blockIdx.y * 128 + w * 32;

  // Q fragments: qf[cs] = Q[q0+qv][16cs + 8hi .. +8)  (64 VGPR)
  f16x8 qf[16];
  {
    const _Float16* qb = qtp + ((size_t)b * N_DIM + q0 + qv) * C_DIM + 8 * hi;
    #pragma unroll
    for (int cs = 0; cs < 16; ++cs) qf[cs] = *(const f16x8*)(qb + 16 * cs);
  }

  // hoisted LDS read bases (byte offsets within a buffer)
  int kb[4];
  #pragma unroll
  for (int t2 = 0; t2 < 4; ++t2)
    kb[t2] = qv * 512 + 16 * (hi ^ (lane & 1)) + 32 * (t2 ^ xx);
  const int vb0 = qv * 64 + 16 * (hi ^ xx);           // mc=0
  const int vb1 = qv * 64 + 16 * ((2 + hi) ^ xx);     // mc=1

  // staging pointers, advanced by constant strides per tile
  const char* kg[4];
  const char* vg[4];
  int dk[4];
  {
    const int k00 = half * 2048;
    #pragma unroll
    for (int j = 0; j < 4; ++j) {
      int l = j * 256 + tid;
      int row = l >> 5, s16 = l & 31;
      int o16 = s16 ^ (row & 7);
      kg[j] = (const char*)(ktp + ((size_t)b * N_DIM + k00 + row) * C_DIM + o16 * 8);
      int c = l >> 2, s4 = l & 3;
      int o4 = s4 ^ ((c >> 1) & 3);
      vg[j] = (const char*)(vvp + ((size_t)b * C_DIM + c) * N_DIM + k00 + o4 * 8);
      dk[j] = l * 16;
    }
  }

#define STAGE(BUF)                                                            \
  {                                                                           \
    char* bb = lds + (BUF) * BUFSZ;                                           \
    _Pragma("unroll")                                                         \
    for (int j = 0; j < 4; ++j) {                                             \
      gload_lds16(kg[j], bb + dk[j]);                                         \
      gload_lds16(vg[j], bb + VOFF + dk[j]);                                  \
      kg[j] += 32 * C_DIM * 2;  /* next 32 K-rows */                          \
      vg[j] += 32 * 2;          /* next 32 m-cols */                          \
    }                                                                         \
  }

  f32x16 acc[8];
  #pragma unroll
  for (int ct = 0; ct < 8; ++ct) acc[ct] = 0.0f;
  float m_run = -1e30f, l_run = 0.f;

  STAGE(0)
  int cur = 0;

  for (int kt = 0; kt < NT; ++kt) {
    __syncthreads();                 // buf[cur] DMA drained; prev compute done
    if (kt + 1 < NT) STAGE(cur ^ 1)
    const char* cb = lds + cur * BUFSZ;

    // QK^T (swapped): S[k-row][q-col]; lane owns q=qv, 16 k-values
    f32x16 S = 0.0f;
    #pragma unroll
    for (int cs = 0; cs < 16; ++cs) {
      f16x8 kf = *(const f16x8*)(cb + kb[cs & 3] + 128 * (cs >> 2));
      S = mfma32(kf, qf[cs], S);
    }

    // online softmax (exp2 units; defer-max THR = 8*log2e)
    float t01 = fmaxf(S[0], S[1]),  t23 = fmaxf(S[2], S[3]);
    float t45 = fmaxf(S[4], S[5]),  t67 = fmaxf(S[6], S[7]);
    float t89 = fmaxf(S[8], S[9]),  tab = fmaxf(S[10], S[11]);
    float tcd = fmaxf(S[12], S[13]), tef = fmaxf(S[14], S[15]);
    float tmax = fmaxf(fmaxf(fmaxf(t01, t23), fmaxf(t45, t67)),
                       fmaxf(fmaxf(t89, tab), fmaxf(tcd, tef)));
    tmax = fmaxf(tmax, __shfl_xor(tmax, 32));
    if (tmax > m_run + 11.541560f) {
      float sc = exp2f(m_run - tmax);
      m_run = tmax;
      l_run *= sc;
      #pragma unroll
      for (int ct = 0; ct < 8; ++ct) {
        #pragma unroll
        for (int r = 0; r < 16; ++r) acc[ct][r] *= sc;
      }
    }
    float e[16];
    #pragma unroll
    for (int r = 0; r < 16; ++r) e[r] = exp2f(S[r] - m_run);
    float ts = ((e[0] + e[1]) + (e[2] + e[3])) + ((e[4] + e[5]) + (e[6] + e[7]))
             + ((e[8] + e[9]) + (e[10] + e[11])) + ((e[12] + e[13]) + (e[14] + e[15]));
    ts += __shfl_xor(ts, 32);
    l_run += ts;

    // pack P -> 8 dwords; lane dword a holds P-dwords d = 4*(a>>1)+(a&1)+2*hi
    unsigned int a0 = pk2(e[0], e[1]),   a1 = pk2(e[2], e[3]);
    unsigned int a2 = pk2(e[4], e[5]),   a3 = pk2(e[6], e[7]);
    unsigned int a4 = pk2(e[8], e[9]),   a5 = pk2(e[10], e[11]);
    unsigned int a6 = pk2(e[12], e[13]), a7 = pk2(e[14], e[15]);
    // exchange with partner lane (lane^32) to build PV B-fragments
    unsigned int R0 = __shfl_xor(hi ? a0 : a2, 32);
    unsigned int R1 = __shfl_xor(hi ? a1 : a3, 32);
    unsigned int R2 = __shfl_xor(hi ? a4 : a6, 32);
    unsigned int R3 = __shfl_xor(hi ? a5 : a7, 32);
    union { unsigned int u[4]; f16x8 v; } pu0, pu1;
    pu0.u[0] = hi ? R0 : a0;  pu0.u[1] = hi ? R1 : a1;
    pu0.u[2] = hi ? a2 : R0;  pu0.u[3] = hi ? a3 : R1;
    pu1.u[0] = hi ? R2 : a4;  pu1.u[1] = hi ? R3 : a5;
    pu1.u[2] = hi ? a6 : R2;  pu1.u[3] = hi ? a7 : R3;

    // PV: acc[ctt] += V[32ctt.., m] * P^T   (2 m-chunks of 16)
    #pragma unroll
    for (int ctt = 0; ctt < 8; ++ctt) {
      f16x8 vf0 = *(const f16x8*)(cb + VOFF + vb0 + 2048 * ctt);
      f16x8 vf1 = *(const f16x8*)(cb + VOFF + vb1 + 2048 * ctt);
      acc[ctt] = mfma32(vf0, pu0.v, acc[ctt]);
      acc[ctt] = mfma32(vf1, pu1.v, acc[ctt]);
    }

    cur ^= 1;
  }

  // epilogue: normalized partial o (fp16) + (m,l) per q
  _Float16* opb = op + (size_t)(half * 8 + b) * C_DIM * N_DIM;
  const float inv = 1.0f / l_run;
  const int n = q0 + qv;
  #pragma unroll
  for (int ctt = 0; ctt < 8; ++ctt) {
    #pragma unroll
    for (int r = 0; r < 16; ++r) {
      int c = 32 * ctt + (r & 3) + 8 * (r >> 2) + 4 * hi;
      opb[(size_t)c * N_DIM + n] = (_Float16)(acc[ctt][r] * inv);
    }
  }
  if (hi == 0)
    ml[(size_t)(half * 8 + b) * N_DIM + n] = make_float2(m_run, l_run);
#undef STAGE
}

// ---------------- kernel 4: merge the two key-halves ----------------
__global__ __launch_bounds__(256) void merge_kernel(
    const _Float16* __restrict__ op, const float2* __restrict__ ml,
    float* __restrict__ out) {
  const int b = blockIdx.x;
  const int n0 = blockIdx.y * 128;
  const int tid = threadIdx.x;
  const int nc = tid & 15;
  const int cl = tid >> 4;
  const int nb = n0 + nc * 8;

  float a0[8], a1[8];
  #pragma unroll
  for (int jj = 0; jj < 8; ++jj) {
    int q = nb + jj;
    float2 h0 = ml[(size_t)b * N_DIM + q];
    float2 h1 = ml[(size_t)(8 + b) * N_DIM + q];
    float M = fmaxf(h0.x, h1.x);
    float e0 = exp2f(h0.x - M) * h0.y;
    float e1 = exp2f(h1.x - M) * h1.y;
    float inv = 1.0f / (e0 + e1);
    a0[jj] = e0 * inv;
    a1[jj] = e1 * inv;
  }
  const _Float16* op0 = op + (size_t)b * C_DIM * N_DIM;
  const _Float16* op1 = op + (size_t)(8 + b) * C_DIM * N_DIM;
  for (int it = 0; it < 16; ++it) {
    int c = cl + it * 16;
    size_t base = (size_t)c * N_DIM + nb;
    f16x8 p0 = *(const f16x8*)(op0 + base);
    f16x8 p1 = *(const f16x8*)(op1 + base);
    float o[8];
    #pragma unroll
    for (int jj = 0; jj < 8; ++jj)
      o[jj] = (float)p0[jj] * a0[jj] + (float)p1[jj] * a1[jj];
    size_t ob = ((size_t)b * C_DIM + c) * N_DIM + nb;
    *(float4*)(out + ob) = make_float4(o[0], o[1], o[2], o[3]);
    *(float4*)(out + ob + 4) = make_float4(o[4], o[5], o[6], o[7]);
  }
}

extern "C" void kernel_launch(void* const* d_in, const int* in_sizes, int n_in,
                              void* d_out, int out_size, void* d_ws, size_t ws_size,
                              hipStream_t stream) {
  const float* x1 = (const float*)d_in[0];
  const float* x2 = (const float*)d_in[1];
  const float* Wq = (const float*)d_in[2];
  const float* bq = (const float*)d_in[3];
  const float* Wk = (const float*)d_in[4];
  const float* bk = (const float*)d_in[5];
  const float* Wv = (const float*)d_in[6];
  const float* bv = (const float*)d_in[7];
  float* out = (float*)d_out;

  char* ws = (char*)d_ws;
  const size_t SZ = (size_t)8 * 4096 * 256 * 2;  // 16.78 MB per fp16 plane
  _Float16* qt  = (_Float16*)(ws + 0 * SZ);
  _Float16* kt  = (_Float16*)(ws + 1 * SZ);
  _Float16* vv  = (_Float16*)(ws + 2 * SZ);
  _Float16* op  = (_Float16*)(ws + 3 * SZ);     // 2 x SZ partial outputs
  float2*   ml  = (float2*)(ws + 5 * SZ);       // 512KB
  _Float16* wsp = (_Float16*)(ws + 3 * SZ);     // overlaps op: proj before attn
  // requires ws_size >= 5*SZ + 524288 = 84,410,368 bytes

  cvt_w3<<<dim3(256, 3), 256, 0, stream>>>(Wq, Wk, Wv, wsp);
  proj3_kernel<<<dim3(32, 8), 512, 0, stream>>>(x1, x2, wsp, bq, bk, bv,
                                                qt, kt, vv);
  attn_kernel<<<dim3(16, 32), 256, 0, stream>>>(qt, kt, vv, op, ml);
  merge_kernel<<<dim3(8, 32), 256, 0, stream>>>(op, ml, out);
}

// Round 12
// 220.576 us; speedup vs baseline: 1.7669x; 1.3031x over previous
//
#include <hip/hip_runtime.h>

// CrossAttention: B=8, C=256, H=W=64, N=4096
// fp16 pipeline, round 12:
//   cvt_w3 -> proj3_kernel (W staged in LDS, dbuf 2x32KB, fixed indexing)
//   -> attn_kernel (32x32x16, key-split x2, COMPILER exp2f/fmaxf softmax —
//   inline-asm v_exp_f32 was the rounds-9..11 correctness bug) -> merge.

#define C_DIM 256
#define N_DIM 4096
#define LOG2E 1.4426950408889634f

using f32x4 = __attribute__((ext_vector_type(4))) float;
using f32x16 = __attribute__((ext_vector_type(16))) float;
using f16x8 = __attribute__((ext_vector_type(8))) _Float16;

__device__ __forceinline__ f32x4 mfmah(f16x8 a, f16x8 b, f32x4 c) {
  return __builtin_amdgcn_mfma_f32_16x16x32_f16(a, b, c, 0, 0, 0);
}
__device__ __forceinline__ f32x16 mfma32(f16x8 a, f16x8 b, f32x16 c) {
  return __builtin_amdgcn_mfma_f32_32x32x16_f16(a, b, c, 0, 0, 0);
}
__device__ __forceinline__ unsigned int pk2(float a, float b) {
  return __builtin_bit_cast(unsigned int, __builtin_amdgcn_cvt_pkrtz(a, b));
}
__device__ __forceinline__ void gload_lds16(const void* g, void* l) {
  __builtin_amdgcn_global_load_lds(
      (const __attribute__((address_space(1))) unsigned int*)g,
      (__attribute__((address_space(3))) unsigned int*)l, 16, 0, 0);
}

// ---------------- kernel 1: convert W to fp16 (Wq scaled by log2e) --------
__global__ __launch_bounds__(256) void cvt_w3(const float* __restrict__ wq,
                                              const float* __restrict__ wk,
                                              const float* __restrict__ wv,
                                              _Float16* __restrict__ dst) {
  int i = blockIdx.x * 256 + threadIdx.x;
  int m = blockIdx.y;
  const float* w = (m == 0) ? wq : ((m == 1) ? wk : wv);
  float s = (m == 0) ? LOG2E : 1.0f;
  dst[m * 65536 + i] = (_Float16)(w[i] * s);
}

// ---------------- kernel 2: all 3 projections, W via LDS ----------------
// grid (32 n-tiles, 8 b) = 256 = 1 block/CU, 512 thr (8 waves x 16 cols).
// x tile 65KB in sx; W staged in 64-row chunks (32KB), dbuf, rows 512B
// (32 x 16B slots), global slot o32 = s32 ^ (row&7), LDS linear.
#define PROW2 130
__global__ __launch_bounds__(512) void proj3_kernel(
    const float* __restrict__ x1, const float* __restrict__ x2,
    const _Float16* __restrict__ wsp,
    const float* __restrict__ bq, const float* __restrict__ bk, const float* __restrict__ bv,
    _Float16* __restrict__ qt, _Float16* __restrict__ kt, _Float16* __restrict__ vv) {
  __shared__ __align__(16) _Float16 sx[256 * PROW2];     // 66,560 B
  __shared__ __align__(16) char swb[2][32768];           // W chunk dbuf
  const int t = threadIdx.x;
  const int n0 = blockIdx.x * 128;
  const int b = blockIdx.y;

  const int w = t >> 6;
  const int lane = t & 63;
  const int li = lane & 15;
  const int lg = lane >> 4;
  const int nloc = w * 16 + li;
  const int n = n0 + nloc;

#define STAGEX(XP)                                                          \
  for (int it = 0; it < 16; ++it) {                                        \
    int chunk = t + 512 * it;                                              \
    int row = chunk >> 5, n4 = chunk & 31;                                 \
    float4 v4 = *((const float4*)((XP) + ((size_t)b * 256 + row) * 4096 + n0) + n4); \
    uint2 pv = make_uint2(pk2(v4.x, v4.y), pk2(v4.z, v4.w));               \
    *(uint2*)(sx + row * PROW2 + n4 * 4) = pv;                             \
  }

#define GATHER(XF)                                                          \
  _Pragma("unroll")                                                         \
  for (int cs = 0; cs < 8; ++cs) {                                         \
    _Pragma("unroll")                                                       \
    for (int jj = 0; jj < 8; ++jj)                                         \
      XF[cs][jj] = sx[(cs * 32 + lg * 8 + jj) * PROW2 + nloc];             \
  }

  // stage W chunk CH (64 rows) into swb[CH&1]; 32 16B slots/row,
  // global slot o32 = s32 ^ (row&7), LDS dst linear (l>>5 / l&31)
#define STAGEW(CH)                                                          \
  {                                                                         \
    const _Float16* wsrc = wsp + (CH) * 16384;                              \
    char* dstb = swb[(CH) & 1];                                             \
    _Pragma("unroll")                                                       \
    for (int j = 0; j < 4; ++j) {                                           \
      int l = j * 512 + t;                                                  \
      int row = l >> 5, s32 = l & 31;                                       \
      int o32 = s32 ^ (row & 7);                                            \
      gload_lds16(wsrc + row * 256 + o32 * 8, dstb + l * 16);               \
    }                                                                       \
  }

  f16x8 xf[8];

  // fragment read: row = otl*16+li (row&7 == li&7), slot (cs*4+lg)^(li&7)
#define WFRAG(OTL, CS)                                                      \
  (*(const f16x8*)(swb[cc & 1] + ((OTL) * 16 + li) * 512 +                  \
                   (((CS) * 4 + lg) ^ (li & 7)) * 16))

  // ---- x1 -> Q ----
  STAGEX(x1)
  STAGEW(0)
  __syncthreads();
  GATHER(xf)
  for (int cc = 0; cc < 4; ++cc) {
    STAGEW(cc + 1)
    #pragma unroll
    for (int otl = 0; otl < 4; ++otl) {
      f32x4 acc = 0.0f;
      #pragma unroll
      for (int cs = 0; cs < 8; ++cs) acc = mfmah(WFRAG(otl, cs), xf[cs], acc);
      int o0 = cc * 64 + otl * 16 + lg * 4;
      union { _Float16 h[4]; ushort4 u; } pk;
      #pragma unroll
      for (int r = 0; r < 4; ++r)
        pk.h[r] = (_Float16)(acc[r] + bq[o0 + r] * LOG2E);
      *(ushort4*)(qt + ((size_t)b * 4096 + n) * 256 + o0) = pk.u;
    }
    __syncthreads();
  }

  // ---- x2 -> K, V ----
  STAGEX(x2)
  __syncthreads();
  GATHER(xf)
  for (int cc = 4; cc < 8; ++cc) {     // Wk chunks
    STAGEW(cc + 1)
    #pragma unroll
    for (int otl = 0; otl < 4; ++otl) {
      f32x4 acc = 0.0f;
      #pragma unroll
      for (int cs = 0; cs < 8; ++cs) acc = mfmah(WFRAG(otl, cs), xf[cs], acc);
      int o0 = (cc - 4) * 64 + otl * 16 + lg * 4;
      union { _Float16 h[4]; ushort4 u; } pk;
      #pragma unroll
      for (int r = 0; r < 4; ++r) pk.h[r] = (_Float16)(acc[r] + bk[o0 + r]);
      *(ushort4*)(kt + ((size_t)b * 4096 + n) * 256 + o0) = pk.u;
    }
    __syncthreads();
  }
  for (int cc = 8; cc < 12; ++cc) {    // Wv chunks
    if (cc < 11) STAGEW(cc + 1)
    #pragma unroll
    for (int otl = 0; otl < 4; ++otl) {
      f32x4 acc = 0.0f;
      #pragma unroll
      for (int cs = 0; cs < 8; ++cs) acc = mfmah(WFRAG(otl, cs), xf[cs], acc);
      int o0 = (cc - 8) * 64 + otl * 16 + lg * 4;
      #pragma unroll
      for (int r = 0; r < 4; ++r)
        vv[((size_t)b * 256 + o0 + r) * 4096 + n] = (_Float16)(acc[r] + bv[o0 + r]);
    }
    __syncthreads();
  }
#undef STAGEX
#undef GATHER
#undef STAGEW
#undef WFRAG
}

// ---------------- kernel 3: flash attention (32x32x16, key-split x2) -------
// grid (16 = b*2+half, 32 qblocks), 256 thr (4 waves x 32 q).
#define NT 64
#define VOFF 16384
#define BUFSZ 32768

__global__ __launch_bounds__(256, 2) void attn_kernel(
    const _Float16* __restrict__ qtp, const _Float16* __restrict__ ktp,
    const _Float16* __restrict__ vvp, _Float16* __restrict__ op,
    float2* __restrict__ ml) {
  __shared__ __align__(16) char lds[2 * BUFSZ];

  const int tid = threadIdx.x;
  const int half = blockIdx.x & 1;
  const int b = blockIdx.x >> 1;
  const int w = tid >> 6;
  const int lane = tid & 63;
  const int qv = lane & 31;
  const int hi = lane >> 5;
  const int xx = (lane >> 1) & 3;
  const int q0 = blockIdx.y * 128 + w * 32;

  // Q fragments (64 VGPR)
  f16x8 qf[16];
  {
    const _Float16* qb = qtp + ((size_t)b * N_DIM + q0 + qv) * C_DIM + 8 * hi;
    #pragma unroll
    for (int cs = 0; cs < 16; ++cs) qf[cs] = *(const f16x8*)(qb + 16 * cs);
  }

  // hoisted LDS read bases
  int kb[4];
  #pragma unroll
  for (int t2 = 0; t2 < 4; ++t2)
    kb[t2] = qv * 512 + 16 * (hi ^ (lane & 1)) + 32 * (t2 ^ xx);
  const int vb0 = qv * 64 + 16 * (hi ^ xx);
  const int vb1 = qv * 64 + 16 * ((2 + hi) ^ xx);

  // staging pointers advanced by constant strides
  const char* kg[4];
  const char* vg[4];
  int dk[4];
  {
    const int k00 = half * 2048;
    #pragma unroll
    for (int j = 0; j < 4; ++j) {
      int l = j * 256 + tid;
      int row = l >> 5, s16 = l & 31;
      int o16 = s16 ^ (row & 7);
      kg[j] = (const char*)(ktp + ((size_t)b * N_DIM + k00 + row) * C_DIM + o16 * 8);
      int c = l >> 2, s4 = l & 3;
      int o4 = s4 ^ ((c >> 1) & 3);
      vg[j] = (const char*)(vvp + ((size_t)b * C_DIM + c) * N_DIM + k00 + o4 * 8);
      dk[j] = l * 16;
    }
  }

#define STAGE(BUF)                                                            \
  {                                                                           \
    char* bb = lds + (BUF) * BUFSZ;                                           \
    _Pragma("unroll")                                                         \
    for (int j = 0; j < 4; ++j) {                                             \
      gload_lds16(kg[j], bb + dk[j]);                                         \
      gload_lds16(vg[j], bb + VOFF + dk[j]);                                  \
      kg[j] += 32 * C_DIM * 2;                                                \
      vg[j] += 32 * 2;                                                        \
    }                                                                         \
  }

  f32x16 acc[8];
  #pragma unroll
  for (int ct = 0; ct < 8; ++ct) acc[ct] = 0.0f;
  float m_run = -1e30f, l_run = 0.f;

  STAGE(0)
  int cur = 0;

  for (int kt = 0; kt < NT; ++kt) {
    __syncthreads();
    if (kt + 1 < NT) STAGE(cur ^ 1)
    const char* cb = lds + cur * BUFSZ;

    // QK^T (swapped)
    f32x16 S = 0.0f;
    #pragma unroll
    for (int cs = 0; cs < 16; ++cs) {
      f16x8 kf = *(const f16x8*)(cb + kb[cs & 3] + 128 * (cs >> 2));
      S = mfma32(kf, qf[cs], S);
    }

    // online softmax (exp2 units; defer-max THR = 8*log2e)
    float t01 = fmaxf(S[0], S[1]),  t23 = fmaxf(S[2], S[3]);
    float t45 = fmaxf(S[4], S[5]),  t67 = fmaxf(S[6], S[7]);
    float t89 = fmaxf(S[8], S[9]),  tab = fmaxf(S[10], S[11]);
    float tcd = fmaxf(S[12], S[13]), tef = fmaxf(S[14], S[15]);
    float tmax = fmaxf(fmaxf(fmaxf(t01, t23), fmaxf(t45, t67)),
                       fmaxf(fmaxf(t89, tab), fmaxf(tcd, tef)));
    tmax = fmaxf(tmax, __shfl_xor(tmax, 32));
    if (tmax > m_run + 11.541560f) {
      float sc = exp2f(m_run - tmax);
      m_run = tmax;
      l_run *= sc;
      #pragma unroll
      for (int ct = 0; ct < 8; ++ct) {
        #pragma unroll
        for (int r = 0; r < 16; ++r) acc[ct][r] *= sc;
      }
    }
    float e[16];
    #pragma unroll
    for (int r = 0; r < 16; ++r) e[r] = exp2f(S[r] - m_run);
    float ts = ((e[0] + e[1]) + (e[2] + e[3])) + ((e[4] + e[5]) + (e[6] + e[7]))
             + ((e[8] + e[9]) + (e[10] + e[11])) + ((e[12] + e[13]) + (e[14] + e[15]));
    ts += __shfl_xor(ts, 32);
    l_run += ts;

    // pack P -> 8 dwords, partner-lane exchange into PV B-fragments
    unsigned int a0 = pk2(e[0], e[1]),   a1 = pk2(e[2], e[3]);
    unsigned int a2 = pk2(e[4], e[5]),   a3 = pk2(e[6], e[7]);
    unsigned int a4 = pk2(e[8], e[9]),   a5 = pk2(e[10], e[11]);
    unsigned int a6 = pk2(e[12], e[13]), a7 = pk2(e[14], e[15]);
    unsigned int R0 = __shfl_xor(hi ? a0 : a2, 32);
    unsigned int R1 = __shfl_xor(hi ? a1 : a3, 32);
    unsigned int R2 = __shfl_xor(hi ? a4 : a6, 32);
    unsigned int R3 = __shfl_xor(hi ? a5 : a7, 32);
    union { unsigned int u[4]; f16x8 v; } pu0, pu1;
    pu0.u[0] = hi ? R0 : a0;  pu0.u[1] = hi ? R1 : a1;
    pu0.u[2] = hi ? a2 : R0;  pu0.u[3] = hi ? a3 : R1;
    pu1.u[0] = hi ? R2 : a4;  pu1.u[1] = hi ? R3 : a5;
    pu1.u[2] = hi ? a6 : R2;  pu1.u[3] = hi ? a7 : R3;

    // PV
    #pragma unroll
    for (int ctt = 0; ctt < 8; ++ctt) {
      f16x8 vf0 = *(const f16x8*)(cb + VOFF + vb0 + 2048 * ctt);
      f16x8 vf1 = *(const f16x8*)(cb + VOFF + vb1 + 2048 * ctt);
      acc[ctt] = mfma32(vf0, pu0.v, acc[ctt]);
      acc[ctt] = mfma32(vf1, pu1.v, acc[ctt]);
    }

    cur ^= 1;
  }

  // epilogue: normalized partial o (fp16) + (m,l)
  _Float16* opb = op + (size_t)(half * 8 + b) * C_DIM * N_DIM;
  const float inv = 1.0f / l_run;
  const int n = q0 + qv;
  #pragma unroll
  for (int ctt = 0; ctt < 8; ++ctt) {
    #pragma unroll
    for (int r = 0; r < 16; ++r) {
      int c = 32 * ctt + (r & 3) + 8 * (r >> 2) + 4 * hi;
      opb[(size_t)c * N_DIM + n] = (_Float16)(acc[ctt][r] * inv);
    }
  }
  if (hi == 0)
    ml[(size_t)(half * 8 + b) * N_DIM + n] = make_float2(m_run, l_run);
#undef STAGE
}

// ---------------- kernel 4: merge the two key-halves ----------------
__global__ __launch_bounds__(256) void merge_kernel(
    const _Float16* __restrict__ op, const float2* __restrict__ ml,
    float* __restrict__ out) {
  const int b = blockIdx.x;
  const int n0 = blockIdx.y * 128;
  const int tid = threadIdx.x;
  const int nc = tid & 15;
  const int cl = tid >> 4;
  const int nb = n0 + nc * 8;

  float a0[8], a1[8];
  #pragma unroll
  for (int jj = 0; jj < 8; ++jj) {
    int q = nb + jj;
    float2 h0 = ml[(size_t)b * N_DIM + q];
    float2 h1 = ml[(size_t)(8 + b) * N_DIM + q];
    float M = fmaxf(h0.x, h1.x);
    float e0 = exp2f(h0.x - M) * h0.y;
    float e1 = exp2f(h1.x - M) * h1.y;
    float inv = 1.0f / (e0 + e1);
    a0[jj] = e0 * inv;
    a1[jj] = e1 * inv;
  }
  const _Float16* op0 = op + (size_t)b * C_DIM * N_DIM;
  const _Float16* op1 = op + (size_t)(8 + b) * C_DIM * N_DIM;
  for (int it = 0; it < 16; ++it) {
    int c = cl + it * 16;
    size_t base = (size_t)c * N_DIM + nb;
    f16x8 p0 = *(const f16x8*)(op0 + base);
    f16x8 p1 = *(const f16x8*)(op1 + base);
    float o[8];
    #pragma unroll
    for (int jj = 0; jj < 8; ++jj)
      o[jj] = (float)p0[jj] * a0[jj] + (float)p1[jj] * a1[jj];
    size_t ob = ((size_t)b * C_DIM + c) * N_DIM + nb;
    *(float4*)(out + ob) = make_float4(o[0], o[1], o[2], o[3]);
    *(float4*)(out + ob + 4) = make_float4(o[4], o[5], o[6], o[7]);
  }
}

extern "C" void kernel_launch(void* const* d_in, const int* in_sizes, int n_in,
                              void* d_out, int out_size, void* d_ws, size_t ws_size,
                              hipStream_t stream) {
  const float* x1 = (const float*)d_in[0];
  const float* x2 = (const float*)d_in[1];
  const float* Wq = (const float*)d_in[2];
  const float* bq = (const float*)d_in[3];
  const float* Wk = (const float*)d_in[4];
  const float* bk = (const float*)d_in[5];
  const float* Wv = (const float*)d_in[6];
  const float* bv = (const float*)d_in[7];
  float* out = (float*)d_out;

  char* ws = (char*)d_ws;
  const size_t SZ = (size_t)8 * 4096 * 256 * 2;  // 16.78 MB per fp16 plane
  _Float16* qt  = (_Float16*)(ws + 0 * SZ);
  _Float16* kt  = (_Float16*)(ws + 1 * SZ);
  _Float16* vv  = (_Float16*)(ws + 2 * SZ);
  _Float16* op  = (_Float16*)(ws + 3 * SZ);     // 2 x SZ partial outputs
  float2*   ml  = (float2*)(ws + 5 * SZ);       // 512KB
  _Float16* wsp = (_Float16*)(ws + 5 * SZ + 524288);  // 384KB W fp16
  // requires ws_size >= 5*SZ + 524288 + 393216 = 84,803,584 bytes

  cvt_w3<<<dim3(256, 3), 256, 0, stream>>>(Wq, Wk, Wv, wsp);
  proj3_kernel<<<dim3(32, 8), 512, 0, stream>>>(x1, x2, wsp, bq, bk, bv,
                                                qt, kt, vv);
  attn_kernel<<<dim3(16, 32), 256, 0, stream>>>(qt, kt, vv, op, ml);
  merge_kernel<<<dim3(8, 32), 256, 0, stream>>>(op, ml, out);
}

// Round 13
// 207.662 us; speedup vs baseline: 1.8768x; 1.0622x over previous
//
#include <hip/hip_runtime.h>

// CrossAttention: B=8, C=256, H=W=64, N=4096
// fp16 pipeline, round 13 (= round 12 + exp2 builtin + setprio):
//   cvt_w3 -> proj3_kernel (W staged in LDS) -> attn_kernel (32x32x16,
//   key-split x2, __builtin_amdgcn_exp2f softmax, setprio MFMA) -> merge.

#define C_DIM 256
#define N_DIM 4096
#define LOG2E 1.4426950408889634f

using f32x4 = __attribute__((ext_vector_type(4))) float;
using f32x16 = __attribute__((ext_vector_type(16))) float;
using f16x8 = __attribute__((ext_vector_type(8))) _Float16;

__device__ __forceinline__ f32x4 mfmah(f16x8 a, f16x8 b, f32x4 c) {
  return __builtin_amdgcn_mfma_f32_16x16x32_f16(a, b, c, 0, 0, 0);
}
__device__ __forceinline__ f32x16 mfma32(f16x8 a, f16x8 b, f32x16 c) {
  return __builtin_amdgcn_mfma_f32_32x32x16_f16(a, b, c, 0, 0, 0);
}
__device__ __forceinline__ unsigned int pk2(float a, float b) {
  return __builtin_bit_cast(unsigned int, __builtin_amdgcn_cvt_pkrtz(a, b));
}
__device__ __forceinline__ void gload_lds16(const void* g, void* l) {
  __builtin_amdgcn_global_load_lds(
      (const __attribute__((address_space(1))) unsigned int*)g,
      (__attribute__((address_space(3))) unsigned int*)l, 16, 0, 0);
}
// single v_exp_f32 via compiler intrinsic (hazards handled by backend —
// unlike inline asm, which was the rounds-9..11 correctness bug)
__device__ __forceinline__ float exp2b(float x) {
  return __builtin_amdgcn_exp2f(x);
}

// ---------------- kernel 1: convert W to fp16 (Wq scaled by log2e) --------
__global__ __launch_bounds__(256) void cvt_w3(const float* __restrict__ wq,
                                              const float* __restrict__ wk,
                                              const float* __restrict__ wv,
                                              _Float16* __restrict__ dst) {
  int i = blockIdx.x * 256 + threadIdx.x;
  int m = blockIdx.y;
  const float* w = (m == 0) ? wq : ((m == 1) ? wk : wv);
  float s = (m == 0) ? LOG2E : 1.0f;
  dst[m * 65536 + i] = (_Float16)(w[i] * s);
}

// ---------------- kernel 2: all 3 projections, W via LDS ----------------
#define PROW2 130
__global__ __launch_bounds__(512) void proj3_kernel(
    const float* __restrict__ x1, const float* __restrict__ x2,
    const _Float16* __restrict__ wsp,
    const float* __restrict__ bq, const float* __restrict__ bk, const float* __restrict__ bv,
    _Float16* __restrict__ qt, _Float16* __restrict__ kt, _Float16* __restrict__ vv) {
  __shared__ __align__(16) _Float16 sx[256 * PROW2];     // 66,560 B
  __shared__ __align__(16) char swb[2][32768];           // W chunk dbuf
  const int t = threadIdx.x;
  const int n0 = blockIdx.x * 128;
  const int b = blockIdx.y;

  const int w = t >> 6;
  const int lane = t & 63;
  const int li = lane & 15;
  const int lg = lane >> 4;
  const int nloc = w * 16 + li;
  const int n = n0 + nloc;

#define STAGEX(XP)                                                          \
  for (int it = 0; it < 16; ++it) {                                        \
    int chunk = t + 512 * it;                                              \
    int row = chunk >> 5, n4 = chunk & 31;                                 \
    float4 v4 = *((const float4*)((XP) + ((size_t)b * 256 + row) * 4096 + n0) + n4); \
    uint2 pv = make_uint2(pk2(v4.x, v4.y), pk2(v4.z, v4.w));               \
    *(uint2*)(sx + row * PROW2 + n4 * 4) = pv;                             \
  }

#define GATHER(XF)                                                          \
  _Pragma("unroll")                                                         \
  for (int cs = 0; cs < 8; ++cs) {                                         \
    _Pragma("unroll")                                                       \
    for (int jj = 0; jj < 8; ++jj)                                         \
      XF[cs][jj] = sx[(cs * 32 + lg * 8 + jj) * PROW2 + nloc];             \
  }

#define STAGEW(CH)                                                          \
  {                                                                         \
    const _Float16* wsrc = wsp + (CH) * 16384;                              \
    char* dstb = swb[(CH) & 1];                                             \
    _Pragma("unroll")                                                       \
    for (int j = 0; j < 4; ++j) {                                           \
      int l = j * 512 + t;                                                  \
      int row = l >> 5, s32 = l & 31;                                       \
      int o32 = s32 ^ (row & 7);                                            \
      gload_lds16(wsrc + row * 256 + o32 * 8, dstb + l * 16);               \
    }                                                                       \
  }

  f16x8 xf[8];

#define WFRAG(OTL, CS)                                                      \
  (*(const f16x8*)(swb[cc & 1] + ((OTL) * 16 + li) * 512 +                  \
                   (((CS) * 4 + lg) ^ (li & 7)) * 16))

  // ---- x1 -> Q ----
  STAGEX(x1)
  STAGEW(0)
  __syncthreads();
  GATHER(xf)
  for (int cc = 0; cc < 4; ++cc) {
    STAGEW(cc + 1)
    #pragma unroll
    for (int otl = 0; otl < 4; ++otl) {
      f32x4 acc = 0.0f;
      #pragma unroll
      for (int cs = 0; cs < 8; ++cs) acc = mfmah(WFRAG(otl, cs), xf[cs], acc);
      int o0 = cc * 64 + otl * 16 + lg * 4;
      union { _Float16 h[4]; ushort4 u; } pk;
      #pragma unroll
      for (int r = 0; r < 4; ++r)
        pk.h[r] = (_Float16)(acc[r] + bq[o0 + r] * LOG2E);
      *(ushort4*)(qt + ((size_t)b * 4096 + n) * 256 + o0) = pk.u;
    }
    __syncthreads();
  }

  // ---- x2 -> K, V ----
  STAGEX(x2)
  __syncthreads();
  GATHER(xf)
  for (int cc = 4; cc < 8; ++cc) {     // Wk chunks
    STAGEW(cc + 1)
    #pragma unroll
    for (int otl = 0; otl < 4; ++otl) {
      f32x4 acc = 0.0f;
      #pragma unroll
      for (int cs = 0; cs < 8; ++cs) acc = mfmah(WFRAG(otl, cs), xf[cs], acc);
      int o0 = (cc - 4) * 64 + otl * 16 + lg * 4;
      union { _Float16 h[4]; ushort4 u; } pk;
      #pragma unroll
      for (int r = 0; r < 4; ++r) pk.h[r] = (_Float16)(acc[r] + bk[o0 + r]);
      *(ushort4*)(kt + ((size_t)b * 4096 + n) * 256 + o0) = pk.u;
    }
    __syncthreads();
  }
  for (int cc = 8; cc < 12; ++cc) {    // Wv chunks
    if (cc < 11) STAGEW(cc + 1)
    #pragma unroll
    for (int otl = 0; otl < 4; ++otl) {
      f32x4 acc = 0.0f;
      #pragma unroll
      for (int cs = 0; cs < 8; ++cs) acc = mfmah(WFRAG(otl, cs), xf[cs], acc);
      int o0 = (cc - 8) * 64 + otl * 16 + lg * 4;
      #pragma unroll
      for (int r = 0; r < 4; ++r)
        vv[((size_t)b * 256 + o0 + r) * 4096 + n] = (_Float16)(acc[r] + bv[o0 + r]);
    }
    __syncthreads();
  }
#undef STAGEX
#undef GATHER
#undef STAGEW
#undef WFRAG
}

// ---------------- kernel 3: flash attention (32x32x16, key-split x2) -------
// grid (16 = b*2+half, 32 qblocks), 256 thr (4 waves x 32 q).
#define NT 64
#define VOFF 16384
#define BUFSZ 32768

__global__ __launch_bounds__(256, 2) void attn_kernel(
    const _Float16* __restrict__ qtp, const _Float16* __restrict__ ktp,
    const _Float16* __restrict__ vvp, _Float16* __restrict__ op,
    float2* __restrict__ ml) {
  __shared__ __align__(16) char lds[2 * BUFSZ];

  const int tid = threadIdx.x;
  const int half = blockIdx.x & 1;
  const int b = blockIdx.x >> 1;
  const int w = tid >> 6;
  const int lane = tid & 63;
  const int qv = lane & 31;
  const int hi = lane >> 5;
  const int xx = (lane >> 1) & 3;
  const int q0 = blockIdx.y * 128 + w * 32;

  // Q fragments (64 VGPR)
  f16x8 qf[16];
  {
    const _Float16* qb = qtp + ((size_t)b * N_DIM + q0 + qv) * C_DIM + 8 * hi;
    #pragma unroll
    for (int cs = 0; cs < 16; ++cs) qf[cs] = *(const f16x8*)(qb + 16 * cs);
  }

  // hoisted LDS read bases
  int kb[4];
  #pragma unroll
  for (int t2 = 0; t2 < 4; ++t2)
    kb[t2] = qv * 512 + 16 * (hi ^ (lane & 1)) + 32 * (t2 ^ xx);
  const int vb0 = qv * 64 + 16 * (hi ^ xx);
  const int vb1 = qv * 64 + 16 * ((2 + hi) ^ xx);

  // staging pointers advanced by constant strides
  const char* kg[4];
  const char* vg[4];
  int dk[4];
  {
    const int k00 = half * 2048;
    #pragma unroll
    for (int j = 0; j < 4; ++j) {
      int l = j * 256 + tid;
      int row = l >> 5, s16 = l & 31;
      int o16 = s16 ^ (row & 7);
      kg[j] = (const char*)(ktp + ((size_t)b * N_DIM + k00 + row) * C_DIM + o16 * 8);
      int c = l >> 2, s4 = l & 3;
      int o4 = s4 ^ ((c >> 1) & 3);
      vg[j] = (const char*)(vvp + ((size_t)b * C_DIM + c) * N_DIM + k00 + o4 * 8);
      dk[j] = l * 16;
    }
  }

#define STAGE(BUF)                                                            \
  {                                                                           \
    char* bb = lds + (BUF) * BUFSZ;                                           \
    _Pragma("unroll")                                                         \
    for (int j = 0; j < 4; ++j) {                                             \
      gload_lds16(kg[j], bb + dk[j]);                                         \
      gload_lds16(vg[j], bb + VOFF + dk[j]);                                  \
      kg[j] += 32 * C_DIM * 2;                                                \
      vg[j] += 32 * 2;                                                        \
    }                                                                         \
  }

  f32x16 acc[8];
  #pragma unroll
  for (int ct = 0; ct < 8; ++ct) acc[ct] = 0.0f;
  float m_run = -1e30f, l_run = 0.f;

  STAGE(0)
  int cur = 0;

  for (int kt = 0; kt < NT; ++kt) {
    __syncthreads();
    if (kt + 1 < NT) STAGE(cur ^ 1)
    const char* cb = lds + cur * BUFSZ;

    // QK^T (swapped)
    f32x16 S = 0.0f;
    __builtin_amdgcn_s_setprio(1);
    #pragma unroll
    for (int cs = 0; cs < 16; ++cs) {
      f16x8 kf = *(const f16x8*)(cb + kb[cs & 3] + 128 * (cs >> 2));
      S = mfma32(kf, qf[cs], S);
    }
    __builtin_amdgcn_s_setprio(0);

    // online softmax (exp2 units; defer-max THR = 8*log2e)
    float t01 = fmaxf(S[0], S[1]),  t23 = fmaxf(S[2], S[3]);
    float t45 = fmaxf(S[4], S[5]),  t67 = fmaxf(S[6], S[7]);
    float t89 = fmaxf(S[8], S[9]),  tab = fmaxf(S[10], S[11]);
    float tcd = fmaxf(S[12], S[13]), tef = fmaxf(S[14], S[15]);
    float tmax = fmaxf(fmaxf(fmaxf(t01, t23), fmaxf(t45, t67)),
                       fmaxf(fmaxf(t89, tab), fmaxf(tcd, tef)));
    tmax = fmaxf(tmax, __shfl_xor(tmax, 32));
    if (tmax > m_run + 11.541560f) {
      float sc = exp2b(m_run - tmax);
      m_run = tmax;
      l_run *= sc;
      #pragma unroll
      for (int ct = 0; ct < 8; ++ct) {
        #pragma unroll
        for (int r = 0; r < 16; ++r) acc[ct][r] *= sc;
      }
    }
    float e[16];
    #pragma unroll
    for (int r = 0; r < 16; ++r) e[r] = exp2b(S[r] - m_run);
    float ts = ((e[0] + e[1]) + (e[2] + e[3])) + ((e[4] + e[5]) + (e[6] + e[7]))
             + ((e[8] + e[9]) + (e[10] + e[11])) + ((e[12] + e[13]) + (e[14] + e[15]));
    ts += __shfl_xor(ts, 32);
    l_run += ts;

    // pack P -> 8 dwords, partner-lane exchange into PV B-fragments
    unsigned int a0 = pk2(e[0], e[1]),   a1 = pk2(e[2], e[3]);
    unsigned int a2 = pk2(e[4], e[5]),   a3 = pk2(e[6], e[7]);
    unsigned int a4 = pk2(e[8], e[9]),   a5 = pk2(e[10], e[11]);
    unsigned int a6 = pk2(e[12], e[13]), a7 = pk2(e[14], e[15]);
    unsigned int R0 = __shfl_xor(hi ? a0 : a2, 32);
    unsigned int R1 = __shfl_xor(hi ? a1 : a3, 32);
    unsigned int R2 = __shfl_xor(hi ? a4 : a6, 32);
    unsigned int R3 = __shfl_xor(hi ? a5 : a7, 32);
    union { unsigned int u[4]; f16x8 v; } pu0, pu1;
    pu0.u[0] = hi ? R0 : a0;  pu0.u[1] = hi ? R1 : a1;
    pu0.u[2] = hi ? a2 : R0;  pu0.u[3] = hi ? a3 : R1;
    pu1.u[0] = hi ? R2 : a4;  pu1.u[1] = hi ? R3 : a5;
    pu1.u[2] = hi ? a6 : R2;  pu1.u[3] = hi ? a7 : R3;

    // PV
    __builtin_amdgcn_s_setprio(1);
    #pragma unroll
    for (int ctt = 0; ctt < 8; ++ctt) {
      f16x8 vf0 = *(const f16x8*)(cb + VOFF + vb0 + 2048 * ctt);
      f16x8 vf1 = *(const f16x8*)(cb + VOFF + vb1 + 2048 * ctt);
      acc[ctt] = mfma32(vf0, pu0.v, acc[ctt]);
      acc[ctt] = mfma32(vf1, pu1.v, acc[ctt]);
    }
    __builtin_amdgcn_s_setprio(0);

    cur ^= 1;
  }

  // epilogue: normalized partial o (fp16) + (m,l)
  _Float16* opb = op + (size_t)(half * 8 + b) * C_DIM * N_DIM;
  const float inv = 1.0f / l_run;
  const int n = q0 + qv;
  #pragma unroll
  for (int ctt = 0; ctt < 8; ++ctt) {
    #pragma unroll
    for (int r = 0; r < 16; ++r) {
      int c = 32 * ctt + (r & 3) + 8 * (r >> 2) + 4 * hi;
      opb[(size_t)c * N_DIM + n] = (_Float16)(acc[ctt][r] * inv);
    }
  }
  if (hi == 0)
    ml[(size_t)(half * 8 + b) * N_DIM + n] = make_float2(m_run, l_run);
#undef STAGE
}

// ---------------- kernel 4: merge the two key-halves ----------------
__global__ __launch_bounds__(256) void merge_kernel(
    const _Float16* __restrict__ op, const float2* __restrict__ ml,
    float* __restrict__ out) {
  const int b = blockIdx.x;
  const int n0 = blockIdx.y * 128;
  const int tid = threadIdx.x;
  const int nc = tid & 15;
  const int cl = tid >> 4;
  const int nb = n0 + nc * 8;

  float a0[8], a1[8];
  #pragma unroll
  for (int jj = 0; jj < 8; ++jj) {
    int q = nb + jj;
    float2 h0 = ml[(size_t)b * N_DIM + q];
    float2 h1 = ml[(size_t)(8 + b) * N_DIM + q];
    float M = fmaxf(h0.x, h1.x);
    float e0 = exp2b(h0.x - M) * h0.y;
    float e1 = exp2b(h1.x - M) * h1.y;
    float inv = 1.0f / (e0 + e1);
    a0[jj] = e0 * inv;
    a1[jj] = e1 * inv;
  }
  const _Float16* op0 = op + (size_t)b * C_DIM * N_DIM;
  const _Float16* op1 = op + (size_t)(8 + b) * C_DIM * N_DIM;
  for (int it = 0; it < 16; ++it) {
    int c = cl + it * 16;
    size_t base = (size_t)c * N_DIM + nb;
    f16x8 p0 = *(const f16x8*)(op0 + base);
    f16x8 p1 = *(const f16x8*)(op1 + base);
    float o[8];
    #pragma unroll
    for (int jj = 0; jj < 8; ++jj)
      o[jj] = (float)p0[jj] * a0[jj] + (float)p1[jj] * a1[jj];
    size_t ob = ((size_t)b * C_DIM + c) * N_DIM + nb;
    *(float4*)(out + ob) = make_float4(o[0], o[1], o[2], o[3]);
    *(float4*)(out + ob + 4) = make_float4(o[4], o[5], o[6], o[7]);
  }
}

extern "C" void kernel_launch(void* const* d_in, const int* in_sizes, int n_in,
                              void* d_out, int out_size, void* d_ws, size_t ws_size,
                              hipStream_t stream) {
  const float* x1 = (const float*)d_in[0];
  const float* x2 = (const float*)d_in[1];
  const float* Wq = (const float*)d_in[2];
  const float* bq = (const float*)d_in[3];
  const float* Wk = (const float*)d_in[4];
  const float* bk = (const float*)d_in[5];
  const float* Wv = (const float*)d_in[6];
  const float* bv = (const float*)d_in[7];
  float* out = (float*)d_out;

  char* ws = (char*)d_ws;
  const size_t SZ = (size_t)8 * 4096 * 256 * 2;  // 16.78 MB per fp16 plane
  _Float16* qt  = (_Float16*)(ws + 0 * SZ);
  _Float16* kt  = (_Float16*)(ws + 1 * SZ);
  _Float16* vv  = (_Float16*)(ws + 2 * SZ);
  _Float16* op  = (_Float16*)(ws + 3 * SZ);     // 2 x SZ partial outputs
  float2*   ml  = (float2*)(ws + 5 * SZ);       // 512KB
  _Float16* wsp = (_Float16*)(ws + 5 * SZ + 524288);  // 384KB W fp16
  // requires ws_size >= 5*SZ + 524288 + 393216 = 84,803,584 bytes

  cvt_w3<<<dim3(256, 3), 256, 0, stream>>>(Wq, Wk, Wv, wsp);
  proj3_kernel<<<dim3(32, 8), 512, 0, stream>>>(x1, x2, wsp, bq, bk, bv,
                                                qt, kt, vv);
  attn_kernel<<<dim3(16, 32), 256, 0, stream>>>(qt, kt, vv, op, ml);
  merge_kernel<<<dim3(8, 32), 256, 0, stream>>>(op, ml, out);
}

// Round 15
// 207.338 us; speedup vs baseline: 1.8798x; 1.0016x over previous
//
#include <hip/hip_runtime.h>

// CrossAttention: B=8, C=256, H=W=64, N=4096
// fp16 pipeline, round 15 (= round 14 with the pls(x,x) self-swap bug fixed):
//   - P-dword exchange: permlane32_swap with DISTINCT operands (safe, saves
//     4 ds_bpermute/iter)
//   - tmax/ts reductions: back to __shfl_xor (pls(x,x) aliases both in-place
//     operands to one register -> swap destroys own half -> exp overflow inf)

#define C_DIM 256
#define N_DIM 4096
#define LOG2E 1.4426950408889634f

using f32x4 = __attribute__((ext_vector_type(4))) float;
using f32x16 = __attribute__((ext_vector_type(16))) float;
using f16x8 = __attribute__((ext_vector_type(8))) _Float16;
using u32x2 = __attribute__((ext_vector_type(2))) unsigned int;

__device__ __forceinline__ f32x4 mfmah(f16x8 a, f16x8 b, f32x4 c) {
  return __builtin_amdgcn_mfma_f32_16x16x32_f16(a, b, c, 0, 0, 0);
}
__device__ __forceinline__ f32x16 mfma32(f16x8 a, f16x8 b, f32x16 c) {
  return __builtin_amdgcn_mfma_f32_32x32x16_f16(a, b, c, 0, 0, 0);
}
__device__ __forceinline__ unsigned int pk2(float a, float b) {
  return __builtin_bit_cast(unsigned int, __builtin_amdgcn_cvt_pkrtz(a, b));
}
__device__ __forceinline__ void gload_lds16(const void* g, void* l) {
  __builtin_amdgcn_global_load_lds(
      (const __attribute__((address_space(1))) unsigned int*)g,
      (__attribute__((address_space(3))) unsigned int*)l, 16, 0, 0);
}
__device__ __forceinline__ float exp2b(float x) {
  return __builtin_amdgcn_exp2f(x);
}
// v_permlane32_swap_b32: new_a = {a_lo, b_lo}, new_b = {a_hi, b_hi}.
// ONLY safe with distinct operands (in-place RW semantics alias otherwise).
__device__ __forceinline__ u32x2 pls(unsigned int a, unsigned int b) {
  return __builtin_amdgcn_permlane32_swap(a, b, false, false);
}

// ---------------- kernel 1: convert W to fp16 (Wq scaled by log2e) --------
__global__ __launch_bounds__(256) void cvt_w3(const float* __restrict__ wq,
                                              const float* __restrict__ wk,
                                              const float* __restrict__ wv,
                                              _Float16* __restrict__ dst) {
  int i = blockIdx.x * 256 + threadIdx.x;
  int m = blockIdx.y;
  const float* w = (m == 0) ? wq : ((m == 1) ? wk : wv);
  float s = (m == 0) ? LOG2E : 1.0f;
  dst[m * 65536 + i] = (_Float16)(w[i] * s);
}

// ---------------- kernel 2: all 3 projections, W via LDS ----------------
#define PROW2 130
__global__ __launch_bounds__(512) void proj3_kernel(
    const float* __restrict__ x1, const float* __restrict__ x2,
    const _Float16* __restrict__ wsp,
    const float* __restrict__ bq, const float* __restrict__ bk, const float* __restrict__ bv,
    _Float16* __restrict__ qt, _Float16* __restrict__ kt, _Float16* __restrict__ vv) {
  __shared__ __align__(16) _Float16 sx[256 * PROW2];     // 66,560 B
  __shared__ __align__(16) char swb[2][32768];           // W chunk dbuf
  const int t = threadIdx.x;
  const int n0 = blockIdx.x * 128;
  const int b = blockIdx.y;

  const int w = t >> 6;
  const int lane = t & 63;
  const int li = lane & 15;
  const int lg = lane >> 4;
  const int nloc = w * 16 + li;
  const int n = n0 + nloc;

#define STAGEX(XP)                                                          \
  for (int it = 0; it < 16; ++it) {                                        \
    int chunk = t + 512 * it;                                              \
    int row = chunk >> 5, n4 = chunk & 31;                                 \
    float4 v4 = *((const float4*)((XP) + ((size_t)b * 256 + row) * 4096 + n0) + n4); \
    uint2 pv = make_uint2(pk2(v4.x, v4.y), pk2(v4.z, v4.w));               \
    *(uint2*)(sx + row * PROW2 + n4 * 4) = pv;                             \
  }

#define GATHER(XF)                                                          \
  _Pragma("unroll")                                                         \
  for (int cs = 0; cs < 8; ++cs) {                                         \
    _Pragma("unroll")                                                       \
    for (int jj = 0; jj < 8; ++jj)                                         \
      XF[cs][jj] = sx[(cs * 32 + lg * 8 + jj) * PROW2 + nloc];             \
  }

#define STAGEW(CH)                                                          \
  {                                                                         \
    const _Float16* wsrc = wsp + (CH) * 16384;                              \
    char* dstb = swb[(CH) & 1];                                             \
    _Pragma("unroll")                                                       \
    for (int j = 0; j < 4; ++j) {                                           \
      int l = j * 512 + t;                                                  \
      int row = l >> 5, s32 = l & 31;                                       \
      int o32 = s32 ^ (row & 7);                                            \
      gload_lds16(wsrc + row * 256 + o32 * 8, dstb + l * 16);               \
    }                                                                       \
  }

  f16x8 xf[8];

#define WFRAG(OTL, CS)                                                      \
  (*(const f16x8*)(swb[cc & 1] + ((OTL) * 16 + li) * 512 +                  \
                   (((CS) * 4 + lg) ^ (li & 7)) * 16))

  // ---- x1 -> Q ----
  STAGEX(x1)
  STAGEW(0)
  __syncthreads();
  GATHER(xf)
  for (int cc = 0; cc < 4; ++cc) {
    STAGEW(cc + 1)
    #pragma unroll
    for (int otl = 0; otl < 4; ++otl) {
      f32x4 acc = 0.0f;
      #pragma unroll
      for (int cs = 0; cs < 8; ++cs) acc = mfmah(WFRAG(otl, cs), xf[cs], acc);
      int o0 = cc * 64 + otl * 16 + lg * 4;
      union { _Float16 h[4]; ushort4 u; } pk;
      #pragma unroll
      for (int r = 0; r < 4; ++r)
        pk.h[r] = (_Float16)(acc[r] + bq[o0 + r] * LOG2E);
      *(ushort4*)(qt + ((size_t)b * 4096 + n) * 256 + o0) = pk.u;
    }
    __syncthreads();
  }

  // ---- x2 -> K, V ----
  STAGEX(x2)
  __syncthreads();
  GATHER(xf)
  for (int cc = 4; cc < 8; ++cc) {     // Wk chunks
    STAGEW(cc + 1)
    #pragma unroll
    for (int otl = 0; otl < 4; ++otl) {
      f32x4 acc = 0.0f;
      #pragma unroll
      for (int cs = 0; cs < 8; ++cs) acc = mfmah(WFRAG(otl, cs), xf[cs], acc);
      int o0 = (cc - 4) * 64 + otl * 16 + lg * 4;
      union { _Float16 h[4]; ushort4 u; } pk;
      #pragma unroll
      for (int r = 0; r < 4; ++r) pk.h[r] = (_Float16)(acc[r] + bk[o0 + r]);
      *(ushort4*)(kt + ((size_t)b * 4096 + n) * 256 + o0) = pk.u;
    }
    __syncthreads();
  }
  for (int cc = 8; cc < 12; ++cc) {    // Wv chunks
    if (cc < 11) STAGEW(cc + 1)
    #pragma unroll
    for (int otl = 0; otl < 4; ++otl) {
      f32x4 acc = 0.0f;
      #pragma unroll
      for (int cs = 0; cs < 8; ++cs) acc = mfmah(WFRAG(otl, cs), xf[cs], acc);
      int o0 = (cc - 8) * 64 + otl * 16 + lg * 4;
      #pragma unroll
      for (int r = 0; r < 4; ++r)
        vv[((size_t)b * 256 + o0 + r) * 4096 + n] = (_Float16)(acc[r] + bv[o0 + r]);
    }
    __syncthreads();
  }
#undef STAGEX
#undef GATHER
#undef STAGEW
#undef WFRAG
}

// ---------------- kernel 3: flash attention (32x32x16, key-split x2) -------
// grid (16 = b*2+half, 32 qblocks), 256 thr (4 waves x 32 q).
#define NT 64
#define VOFF 16384
#define BUFSZ 32768

__global__ __launch_bounds__(256, 2) void attn_kernel(
    const _Float16* __restrict__ qtp, const _Float16* __restrict__ ktp,
    const _Float16* __restrict__ vvp, _Float16* __restrict__ op,
    float2* __restrict__ ml) {
  __shared__ __align__(16) char lds[2 * BUFSZ];

  const int tid = threadIdx.x;
  const int half = blockIdx.x & 1;
  const int b = blockIdx.x >> 1;
  const int w = tid >> 6;
  const int lane = tid & 63;
  const int qv = lane & 31;
  const int hi = lane >> 5;
  const int xx = (lane >> 1) & 3;
  const int q0 = blockIdx.y * 128 + w * 32;

  // Q fragments (64 VGPR)
  f16x8 qf[16];
  {
    const _Float16* qb = qtp + ((size_t)b * N_DIM + q0 + qv) * C_DIM + 8 * hi;
    #pragma unroll
    for (int cs = 0; cs < 16; ++cs) qf[cs] = *(const f16x8*)(qb + 16 * cs);
  }

  // hoisted LDS read bases
  int kb[4];
  #pragma unroll
  for (int t2 = 0; t2 < 4; ++t2)
    kb[t2] = qv * 512 + 16 * (hi ^ (lane & 1)) + 32 * (t2 ^ xx);
  const int vb0 = qv * 64 + 16 * (hi ^ xx);
  const int vb1 = qv * 64 + 16 * ((2 + hi) ^ xx);

  // staging pointers advanced by constant strides
  const char* kg[4];
  const char* vg[4];
  int dk[4];
  {
    const int k00 = half * 2048;
    #pragma unroll
    for (int j = 0; j < 4; ++j) {
      int l = j * 256 + tid;
      int row = l >> 5, s16 = l & 31;
      int o16 = s16 ^ (row & 7);
      kg[j] = (const char*)(ktp + ((size_t)b * N_DIM + k00 + row) * C_DIM + o16 * 8);
      int c = l >> 2, s4 = l & 3;
      int o4 = s4 ^ ((c >> 1) & 3);
      vg[j] = (const char*)(vvp + ((size_t)b * C_DIM + c) * N_DIM + k00 + o4 * 8);
      dk[j] = l * 16;
    }
  }

#define STAGE(BUF)                                                            \
  {                                                                           \
    char* bb = lds + (BUF) * BUFSZ;                                           \
    _Pragma("unroll")                                                         \
    for (int j = 0; j < 4; ++j) {                                             \
      gload_lds16(kg[j], bb + dk[j]);                                         \
      gload_lds16(vg[j], bb + VOFF + dk[j]);                                  \
      kg[j] += 32 * C_DIM * 2;                                                \
      vg[j] += 32 * 2;                                                        \
    }                                                                         \
  }

  f32x16 acc[8];
  #pragma unroll
  for (int ct = 0; ct < 8; ++ct) acc[ct] = 0.0f;
  float m_run = -1e30f, l_run = 0.f;

  STAGE(0)
  int cur = 0;

  for (int kt = 0; kt < NT; ++kt) {
    __syncthreads();
    if (kt + 1 < NT) STAGE(cur ^ 1)
    const char* cb = lds + cur * BUFSZ;

    // QK^T (swapped)
    f32x16 S = 0.0f;
    __builtin_amdgcn_s_setprio(1);
    #pragma unroll
    for (int cs = 0; cs < 16; ++cs) {
      f16x8 kf = *(const f16x8*)(cb + kb[cs & 3] + 128 * (cs >> 2));
      S = mfma32(kf, qf[cs], S);
    }
    __builtin_amdgcn_s_setprio(0);

    // online softmax (exp2 units; defer-max THR = 8*log2e)
    float t01 = fmaxf(S[0], S[1]),  t23 = fmaxf(S[2], S[3]);
    float t45 = fmaxf(S[4], S[5]),  t67 = fmaxf(S[6], S[7]);
    float t89 = fmaxf(S[8], S[9]),  tab = fmaxf(S[10], S[11]);
    float tcd = fmaxf(S[12], S[13]), tef = fmaxf(S[14], S[15]);
    float tmax = fmaxf(fmaxf(fmaxf(t01, t23), fmaxf(t45, t67)),
                       fmaxf(fmaxf(t89, tab), fmaxf(tcd, tef)));
    tmax = fmaxf(tmax, __shfl_xor(tmax, 32));   // safe cross-half reduce
    if (tmax > m_run + 11.541560f) {
      float sc = exp2b(m_run - tmax);
      m_run = tmax;
      l_run *= sc;
      #pragma unroll
      for (int ct = 0; ct < 8; ++ct) {
        #pragma unroll
        for (int r = 0; r < 16; ++r) acc[ct][r] *= sc;
      }
    }
    float e[16];
    #pragma unroll
    for (int r = 0; r < 16; ++r) e[r] = exp2b(S[r] - m_run);
    float ts = ((e[0] + e[1]) + (e[2] + e[3])) + ((e[4] + e[5]) + (e[6] + e[7]))
             + ((e[8] + e[9]) + (e[10] + e[11])) + ((e[12] + e[13]) + (e[14] + e[15]));
    ts += __shfl_xor(ts, 32);                   // safe cross-half reduce
    l_run += ts;

    // pack P -> 8 dwords; permlane32_swap (distinct operands) builds both
    // PV B-fragment halves per op: new_a = {a_lo,b_lo}, new_b = {a_hi,b_hi}
    unsigned int a0 = pk2(e[0], e[1]),   a1 = pk2(e[2], e[3]);
    unsigned int a2 = pk2(e[4], e[5]),   a3 = pk2(e[6], e[7]);
    unsigned int a4 = pk2(e[8], e[9]),   a5 = pk2(e[10], e[11]);
    unsigned int a6 = pk2(e[12], e[13]), a7 = pk2(e[14], e[15]);
    u32x2 e02 = pls(a0, a2);
    u32x2 e13 = pls(a1, a3);
    u32x2 e46 = pls(a4, a6);
    u32x2 e57 = pls(a5, a7);
    union { unsigned int u[4]; f16x8 v; } pu0, pu1;
    pu0.u[0] = e02[0];  pu0.u[1] = e13[0];
    pu0.u[2] = e02[1];  pu0.u[3] = e13[1];
    pu1.u[0] = e46[0];  pu1.u[1] = e57[0];
    pu1.u[2] = e46[1];  pu1.u[3] = e57[1];

    // PV
    __builtin_amdgcn_s_setprio(1);
    #pragma unroll
    for (int ctt = 0; ctt < 8; ++ctt) {
      f16x8 vf0 = *(const f16x8*)(cb + VOFF + vb0 + 2048 * ctt);
      f16x8 vf1 = *(const f16x8*)(cb + VOFF + vb1 + 2048 * ctt);
      acc[ctt] = mfma32(vf0, pu0.v, acc[ctt]);
      acc[ctt] = mfma32(vf1, pu1.v, acc[ctt]);
    }
    __builtin_amdgcn_s_setprio(0);

    cur ^= 1;
  }

  // epilogue: normalized partial o (fp16) + (m,l)
  _Float16* opb = op + (size_t)(half * 8 + b) * C_DIM * N_DIM;
  const float inv = 1.0f / l_run;
  const int n = q0 + qv;
  #pragma unroll
  for (int ctt = 0; ctt < 8; ++ctt) {
    #pragma unroll
    for (int r = 0; r < 16; ++r) {
      int c = 32 * ctt + (r & 3) + 8 * (r >> 2) + 4 * hi;
      opb[(size_t)c * N_DIM + n] = (_Float16)(acc[ctt][r] * inv);
    }
  }
  if (hi == 0)
    ml[(size_t)(half * 8 + b) * N_DIM + n] = make_float2(m_run, l_run);
#undef STAGE
}

// ---------------- kernel 4: merge the two key-halves ----------------
__global__ __launch_bounds__(256) void merge_kernel(
    const _Float16* __restrict__ op, const float2* __restrict__ ml,
    float* __restrict__ out) {
  const int b = blockIdx.x;
  const int n0 = blockIdx.y * 128;
  const int tid = threadIdx.x;
  const int nc = tid & 15;
  const int cl = tid >> 4;
  const int nb = n0 + nc * 8;

  float a0[8], a1[8];
  #pragma unroll
  for (int jj = 0; jj < 8; ++jj) {
    int q = nb + jj;
    float2 h0 = ml[(size_t)b * N_DIM + q];
    float2 h1 = ml[(size_t)(8 + b) * N_DIM + q];
    float M = fmaxf(h0.x, h1.x);
    float e0 = exp2b(h0.x - M) * h0.y;
    float e1 = exp2b(h1.x - M) * h1.y;
    float inv = 1.0f / (e0 + e1);
    a0[jj] = e0 * inv;
    a1[jj] = e1 * inv;
  }
  const _Float16* op0 = op + (size_t)b * C_DIM * N_DIM;
  const _Float16* op1 = op + (size_t)(8 + b) * C_DIM * N_DIM;
  for (int it = 0; it < 16; ++it) {
    int c = cl + it * 16;
    size_t base = (size_t)c * N_DIM + nb;
    f16x8 p0 = *(const f16x8*)(op0 + base);
    f16x8 p1 = *(const f16x8*)(op1 + base);
    float o[8];
    #pragma unroll
    for (int jj = 0; jj < 8; ++jj)
      o[jj] = (float)p0[jj] * a0[jj] + (float)p1[jj] * a1[jj];
    size_t ob = ((size_t)b * C_DIM + c) * N_DIM + nb;
    *(float4*)(out + ob) = make_float4(o[0], o[1], o[2], o[3]);
    *(float4*)(out + ob + 4) = make_float4(o[4], o[5], o[6], o[7]);
  }
}

extern "C" void kernel_launch(void* const* d_in, const int* in_sizes, int n_in,
                              void* d_out, int out_size, void* d_ws, size_t ws_size,
                              hipStream_t stream) {
  const float* x1 = (const float*)d_in[0];
  const float* x2 = (const float*)d_in[1];
  const float* Wq = (const float*)d_in[2];
  const float* bq = (const float*)d_in[3];
  const float* Wk = (const float*)d_in[4];
  const float* bk = (const float*)d_in[5];
  const float* Wv = (const float*)d_in[6];
  const float* bv = (const float*)d_in[7];
  float* out = (float*)d_out;

  char* ws = (char*)d_ws;
  const size_t SZ = (size_t)8 * 4096 * 256 * 2;  // 16.78 MB per fp16 plane
  _Float16* qt  = (_Float16*)(ws + 0 * SZ);
  _Float16* kt  = (_Float16*)(ws + 1 * SZ);
  _Float16* vv  = (_Float16*)(ws + 2 * SZ);
  _Float16* op  = (_Float16*)(ws + 3 * SZ);     // 2 x SZ partial outputs
  float2*   ml  = (float2*)(ws + 5 * SZ);       // 512KB
  _Float16* wsp = (_Float16*)(ws + 5 * SZ + 524288);  // 384KB W fp16
  // requires ws_size >= 5*SZ + 524288 + 393216 = 84,803,584 bytes

  cvt_w3<<<dim3(256, 3), 256, 0, stream>>>(Wq, Wk, Wv, wsp);
  proj3_kernel<<<dim3(32, 8), 512, 0, stream>>>(x1, x2, wsp, bq, bk, bv,
                                                qt, kt, vv);
  attn_kernel<<<dim3(16, 32), 256, 0, stream>>>(qt, kt, vv, op, ml);
  merge_kernel<<<dim3(8, 32), 256, 0, stream>>>(op, ml, out);
}